// Round 10
// baseline (76.385 us; speedup 1.0000x reference)
//
#include <hip/hip_runtime.h>
#include <stdint.h>

#define HIDDEN 512
#define NDRUG 2000
#define NREACT 10000
#define NEDGE 400000

// bucketed near-sort: 313 used buckets x 32 cols each (c>>5), padded to 320
#define NBKT 320
#define SLOT 2048                 // capacity per bucket (mean ~1280, sigma ~36; +21 sigma)
#define CSTRIDE 16                // cursor padded to 1 int per 64B cache line
#define NSCAT 128                 // scatter blocks (LDS-aggregated)
#define EPB ((NEDGE + NSCAT - 1) / NSCAT)   // 3125 edges per scatter block

// edge kernel: 2 blocks per bucket, 512 threads, in-LDS col sort + Hr in LDS
#define BPB2 2
#define EBLK (NBKT * BPB2)        // 640
#define MAXSL 1024                // max slice entries = ceil(SLOT/BPB2)
#define HRSTRIDE 520              // f16 elems per LDS hr row (512 + 8 pad)
#define ETHREADS 512

#define GEMMBLKS 380              // gemm blocks in fused gemm_scatter grid

typedef __attribute__((ext_vector_type(8))) _Float16 f16x8;
typedef __attribute__((ext_vector_type(2))) _Float16 f16x2;
typedef __attribute__((ext_vector_type(4))) float f32x4;
typedef __attribute__((ext_vector_type(8))) float f32x8;
typedef __attribute__((ext_vector_type(4))) float float4v;

#if defined(__has_builtin)
#if __has_builtin(__builtin_amdgcn_fdot2)
#define HAVE_FDOT2 1
#endif
#endif

// ---------------- init padded cursors: cursor[b*CSTRIDE] = b*SLOT ----------------
__global__ __launch_bounds__(256) void init_cursor(int* __restrict__ cursor) {
  int i = blockIdx.x * blockDim.x + threadIdx.x;
  if (i < NBKT) cursor[i * CSTRIDE] = i * SLOT;
}

// ---------------- fused gemm (f32 inputs, f16 MFMA) + scatter ----------------
// blocks [0,380): GEMM  H = z @ W1half^T (+b1 for drug panel), output f16
// blocks [380,380+NSCAT): LDS-aggregated bucket scatter of edges
#define BM 128
#define BN 128
#define BK 32

__global__ __launch_bounds__(256) void gemm_scatter(
    const float* __restrict__ z_drug, const float* __restrict__ z_react,
    const float* __restrict__ W1,     // (512 out) x (1024 in): [o][0:512]=L, [o][512:1024]=R
    const float* __restrict__ bias,
    const int* __restrict__ row, const int* __restrict__ col,
    _Float16* __restrict__ Hd, _Float16* __restrict__ Hr,
    int* __restrict__ cursor, uint64_t* __restrict__ pk)
{
  __shared__ float As[BM * BK];    // 16 KB (f32 staging)
  __shared__ float Bs[BN * BK];    // 16 KB
  __shared__ int lhist[NBKT];
  __shared__ int lbase[NBKT];

  const int bid = blockIdx.x;
  const int tid = threadIdx.x;

  if (bid >= GEMMBLKS) {
    // ---- scatter branch: block handles edges [e0, e1)
    const int sb = bid - GEMMBLKS;
    const int e0 = sb * EPB;
    const int e1 = (e0 + EPB < NEDGE) ? e0 + EPB : NEDGE;
    for (int i = tid; i < NBKT; i += 256) lhist[i] = 0;
    __syncthreads();
    for (int e = e0 + tid; e < e1; e += 256)
      atomicAdd(&lhist[col[e] >> 5], 1);
    __syncthreads();
    for (int i = tid; i < NBKT; i += 256) {
      int cnt = lhist[i];
      lbase[i] = cnt ? atomicAdd(&cursor[i * CSTRIDE], cnt) : 0;  // reserve range (padded line)
      lhist[i] = 0;                                               // reuse as local offset
    }
    __syncthreads();
    for (int e = e0 + tid; e < e1; e += 256) {
      int c = col[e];
      int r = row[e];
      int bkt = c >> 5;
      int lo = atomicAdd(&lhist[bkt], 1);
      pk[lbase[bkt] + lo] = ((uint64_t)e << 25) | ((uint64_t)r << 14) | (uint64_t)c;
    }
    return;
  }

  // ---- gemm branch: flat [0,64) -> drug (16 mb x 4 nb), [64,380) -> reaction (79 mb x 4 nb)
  const int z = (bid >= 64) ? 1 : 0;
  const int t = z ? bid - 64 : bid;
  const int mb = t >> 2;
  const int nb = t & 3;
  const int M = (z == 0) ? NDRUG : NREACT;
  const float* A = (z == 0) ? z_drug : z_react;
  const int boff = (z == 0) ? 0 : HIDDEN;      // left half for drug, right half for reaction
  _Float16* C = (z == 0) ? Hd : Hr;
  const bool has_bias = (z == 0);
  const int K = HIDDEN, N = HIDDEN;

  const int lane = tid & 63;
  const int wid = tid >> 6;
  const int wm = wid >> 1;
  const int wn = wid & 1;

  f32x4 acc[4][4];
#pragma unroll
  for (int i = 0; i < 4; ++i)
#pragma unroll
    for (int j = 0; j < 4; ++j) acc[i][j] = (f32x4){0.f, 0.f, 0.f, 0.f};

  const int row0 = mb * BM;
  const int col0 = nb * BN;
  const int srow8 = lane >> 3;          // 0..7 (row within 8-row stripe)
  const int scol4 = (lane & 7) * 4;     // f32 col within 32-wide row

  for (int kt = 0; kt < K; kt += BK) {
    // stage A (128x32 f32) and B (128x32 f32): 4 calls per wave per matrix, 1KB each
#pragma unroll
    for (int i = 0; i < 4; ++i) {
      int rA = row0 + wid * 32 + i * 8 + srow8;
      rA = rA < M ? rA : M - 1;                       // clamp for ragged M
      const float* gA = A + (size_t)rA * K + kt + scol4;
      float* lA = As + (wid * 32 + i * 8) * BK;       // wave-uniform base; HW adds lane*16B
      __builtin_amdgcn_global_load_lds(
          (const __attribute__((address_space(1))) void*)gA,
          (__attribute__((address_space(3))) void*)lA, 16, 0, 0);
      int rB = col0 + wid * 32 + i * 8 + srow8;       // N=512, exact
      const float* gB = W1 + (size_t)rB * (2 * HIDDEN) + boff + kt + scol4;
      float* lB = Bs + (wid * 32 + i * 8) * BK;
      __builtin_amdgcn_global_load_lds(
          (const __attribute__((address_space(1))) void*)gB,
          (__attribute__((address_space(3))) void*)lB, 16, 0, 0);
    }
    __syncthreads();

    const int fr = lane & 15;
    const int kg = (lane >> 4) * 8;
    f16x8 af[4], bfr[4];
#pragma unroll
    for (int mi = 0; mi < 4; ++mi) {
      f32x8 v = *reinterpret_cast<const f32x8*>(As + (wm * 64 + mi * 16 + fr) * BK + kg);
      af[mi] = __builtin_convertvector(v, f16x8);
    }
#pragma unroll
    for (int ni = 0; ni < 4; ++ni) {
      f32x8 v = *reinterpret_cast<const f32x8*>(Bs + (wn * 64 + ni * 16 + fr) * BK + kg);
      bfr[ni] = __builtin_convertvector(v, f16x8);
    }
#pragma unroll
    for (int mi = 0; mi < 4; ++mi)
#pragma unroll
      for (int ni = 0; ni < 4; ++ni)
        acc[mi][ni] = __builtin_amdgcn_mfma_f32_16x16x32_f16(af[mi], bfr[ni], acc[mi][ni], 0, 0, 0);
    __syncthreads();
  }

  const int crow = (lane >> 4) * 4;
  const int ccol = lane & 15;
#pragma unroll
  for (int ni = 0; ni < 4; ++ni) {
    const int gc = col0 + wn * 64 + ni * 16 + ccol;
    const float bv = has_bias ? bias[gc] : 0.0f;
#pragma unroll
    for (int mi = 0; mi < 4; ++mi) {
#pragma unroll
      for (int j = 0; j < 4; ++j) {
        const int gr = row0 + wm * 64 + mi * 16 + crow + j;
        if (gr < M) C[(size_t)gr * N + gc] = (_Float16)(acc[mi][ni][j] + bv);
      }
    }
  }
}

// ---------------- edge kernel: 512 thr, in-LDS col sort, Hr in LDS, static quad map ----
__global__ __launch_bounds__(ETHREADS) void edge_kernel(
    const _Float16* __restrict__ Hd, const _Float16* __restrict__ Hr,
    const uint64_t* __restrict__ pk, const int* __restrict__ cursor,
    const float* __restrict__ W2, const float* __restrict__ b2,
    float* __restrict__ out)
{
  __shared__ _Float16 hrs[32 * HRSTRIDE];     // 33.3 KB: the bucket's 32 Hr rows (padded)
  __shared__ uint64_t raw[MAXSL];             // 8 KB
  __shared__ uint64_t spk[MAXSL];             // 8 KB col-sorted
  __shared__ int qdesc[MAXSL / 4 + 32];       // quad descriptors
  __shared__ int cnt[32], cb[32], cnt2[32], qoff[32];
  __shared__ int nqs;

  // bucket->XCD chunked mapping: XCD x owns buckets [x*40, x*40+40)
  const int bid = blockIdx.x;
  const int xcd = bid & 7;
  const int idx = bid >> 3;                 // 0..79
  const int bucket = xcd * 40 + (idx >> 1);
  const int slice = idx & 1;
  const int base = bucket * SLOT;
  const int count = cursor[bucket * CSTRIDE] - base;   // pre-biased cursor
  const int per = (count + BPB2 - 1) / BPB2;
  const int s = slice * per;
  const int e_end0 = (s + per < count) ? s + per : count;
  const int n = (e_end0 > s) ? e_end0 - s : 0;

  const int tid = threadIdx.x;
  const int lane = tid & 63;
  const int li = lane & 15;
  const int wv = tid >> 6;                  // 0..7
  const int gid = wv * 4 + (lane >> 4);     // 0..31: static group id

  // ---- issue Hr preload: wave wv loads rows [wv*4, wv*4+4), one global_load_lds per row
#pragma unroll
  for (int rr2 = 0; rr2 < 4; ++rr2) {
    int rr = wv * 4 + rr2;
    int gr = bucket * 32 + rr;
    gr = (gr < NREACT) ? gr : NREACT - 1;   // clamp (empty tail buckets)
    const _Float16* src = Hr + (size_t)gr * HIDDEN + lane * 8;
    _Float16* dst = hrs + rr * HRSTRIDE;    // 1040B row stride, 16B aligned
    __builtin_amdgcn_global_load_lds(
        (const __attribute__((address_space(1))) void*)src,
        (__attribute__((address_space(3))) void*)dst, 16, 0, 0);
  }

  // ---- W2 fragment (global, L2-hot): lane covers elems li*8 + 128k
  f16x8 w2v[4];
#pragma unroll
  for (int k = 0; k < 4; ++k) {
    const float* p = W2 + li * 8 + k * 128;
    f16x8 q;
#pragma unroll
    for (int j = 0; j < 8; ++j) q[j] = (_Float16)p[j];
    w2v[k] = q;
  }
  const float bias2 = *b2;
  const f16x8 zero8 = (f16x8)(_Float16)0;

  // ---- in-LDS counting sort by local col (c & 31)
  if (tid < 32) { cnt[tid] = 0; cnt2[tid] = 0; }
  __syncthreads();
  for (int i = tid; i < n; i += ETHREADS) {
    uint64_t p = pk[base + s + i];
    raw[i] = p;
    atomicAdd(&cnt[(int)(p & 31)], 1);
  }
  __syncthreads();
  if (tid == 0) {
    int acc = 0, qa = 0;
    for (int j = 0; j < 32; ++j) {
      cb[j] = acc; acc += cnt[j];
      qoff[j] = qa; qa += (cnt[j] + 3) >> 2;
    }
    nqs = qa;
  }
  __syncthreads();
  for (int i = tid; i < n; i += ETHREADS) {
    uint64_t p = raw[i];
    int lc = (int)(p & 31);
    int lo = atomicAdd(&cnt2[lc], 1);
    spk[cb[lc] + lo] = p;
  }
  __syncthreads();
  if (tid < 32) {
    int j = tid, st = cb[j], len = cnt[j], o = qoff[j];
    for (int q = 0; q < len; q += 4) {
      int cn = len - q; cn = (cn < 4) ? cn : 4;
      qdesc[o++] = j | ((st + q) << 5) | (cn << 16);
    }
  }
  __syncthreads();   // also drains vmcnt -> hrs ready

  // ---- process quads, statically strided: group gid takes quads gid, gid+32, ...
  const int nq = nqs;
  for (int q = gid; q < nq; q += 32) {
    const int d = qdesc[q];
    const int lc = d & 31;
    const int st = (d >> 5) & 2047;
    const int cn = (d >> 16) & 7;

    const _Float16* hd[4];
    int si[4];
#pragma unroll
    for (int j = 0; j < 4; ++j) {
      int jj = (j < cn) ? j : cn - 1;
      uint64_t p = spk[st + jj];
      si[j] = (int)(p >> 25);
      hd[j] = Hd + (size_t)((p >> 14) & 0x7FF) * HIDDEN;
    }

    // prefetch the whole quad working set: 4 edges x 4 k-steps
    f16x8 vd[4][4];
#pragma unroll
    for (int j = 0; j < 4; ++j)
#pragma unroll
      for (int k = 0; k < 4; ++k)
        vd[j][k] = *reinterpret_cast<const f16x8*>(hd[j] + li * 8 + k * 128);

    // hr fragment from LDS (shared by the quad's 4 edges)
    f16x8 hv[4];
#pragma unroll
    for (int k = 0; k < 4; ++k)
      hv[k] = *reinterpret_cast<const f16x8*>(hrs + lc * HRSTRIDE + li * 8 + k * 128);

    float acc[4] = {0.f, 0.f, 0.f, 0.f};
#pragma unroll
    for (int j = 0; j < 4; ++j) {
#pragma unroll
      for (int k = 0; k < 4; ++k) {
        f16x8 t = __builtin_elementwise_max(vd[j][k] + hv[k], zero8);
#if defined(HAVE_FDOT2)
#pragma unroll
        for (int qq = 0; qq < 4; ++qq) {
          f16x2 wp = {w2v[k][2 * qq], w2v[k][2 * qq + 1]};
          f16x2 sp = {t[2 * qq], t[2 * qq + 1]};
          acc[j] = __builtin_amdgcn_fdot2(sp, wp, acc[j], false);
        }
#else
#pragma unroll
        for (int qq = 0; qq < 8; ++qq)
          acc[j] += (float)t[qq] * (float)w2v[k][qq];
#endif
      }
    }
#pragma unroll
    for (int off = 8; off >= 1; off >>= 1) {
#pragma unroll
      for (int j = 0; j < 4; ++j) acc[j] += __shfl_xor(acc[j], off);
    }
    if (li == 0) {
      for (int j = 0; j < cn; ++j) out[si[j]] = acc[j] + bias2;
    }
  }
}

extern "C" void kernel_launch(void* const* d_in, const int* in_sizes, int n_in,
                              void* d_out, int out_size, void* d_ws, size_t ws_size,
                              hipStream_t stream) {
  const float* z_drug  = (const float*)d_in[0];
  const float* z_react = (const float*)d_in[1];
  const int*   row     = (const int*)d_in[2];
  const int*   col     = (const int*)d_in[3];
  const float* W1      = (const float*)d_in[4];
  const float* b1      = (const float*)d_in[5];
  const float* W2      = (const float*)d_in[6];
  const float* b2      = (const float*)d_in[7];
  float* out = (float*)d_out;

  char* ws = (char*)d_ws;
  size_t off = 0;
  auto alloc = [&](size_t bytes) {
    void* p = ws + off;
    off += (bytes + 255) & ~(size_t)255;
    return p;
  };
  _Float16* Hd   = (_Float16*)alloc((size_t)NDRUG * HIDDEN * 2);
  _Float16* Hr   = (_Float16*)alloc((size_t)NREACT * HIDDEN * 2);
  int*      cursor = (int*)alloc((size_t)NBKT * CSTRIDE * 4);       // 20 KB padded
  uint64_t* pk     = (uint64_t*)alloc((size_t)NBKT * SLOT * 8);     // 5.2 MB

  init_cursor<<<2, 256, 0, stream>>>(cursor);
  gemm_scatter<<<GEMMBLKS + NSCAT, 256, 0, stream>>>(z_drug, z_react, W1, b1,
                                                     row, col, Hd, Hr, cursor, pk);
  edge_kernel<<<EBLK, ETHREADS, 0, stream>>>(Hd, Hr, pk, cursor, W2, b2, out);
}

// Round 11
// 70.221 us; speedup vs baseline: 1.0878x; 1.0878x over previous
//
#include <hip/hip_runtime.h>
#include <stdint.h>

#define HIDDEN 512
#define NDRUG 2000
#define NREACT 10000
#define NEDGE 400000

// bucketed near-sort: 313 used buckets x 32 cols each (c>>5), padded to 320
#define NBKT 320
#define SLOT 2048                 // capacity per bucket (mean ~1280, sigma ~36; +21 sigma)
#define CSTRIDE 16                // cursor padded to 1 int per 64B cache line
#define NSCAT 128                 // scatter blocks (LDS-aggregated)
#define EPB ((NEDGE + NSCAT - 1) / NSCAT)   // 3125 edges per scatter block

// edge kernel: 2 blocks per bucket, 512 threads, in-LDS col sort + Hr in LDS
#define BPB2 2
#define EBLK (NBKT * BPB2)        // 640
#define MAXSL 1024                // max slice entries = ceil(SLOT/BPB2)
#define HRSTRIDE 520              // f16 elems per LDS hr row (512 + 8 pad)
#define ETHREADS 512

#define GEMMBLKS 380              // gemm blocks in fused gemm_scatter grid

typedef __attribute__((ext_vector_type(8))) _Float16 f16x8;
typedef __attribute__((ext_vector_type(2))) _Float16 f16x2;
typedef __attribute__((ext_vector_type(4))) float f32x4;
typedef __attribute__((ext_vector_type(8))) float f32x8;
typedef __attribute__((ext_vector_type(4))) float float4v;

#if defined(__has_builtin)
#if __has_builtin(__builtin_amdgcn_fdot2)
#define HAVE_FDOT2 1
#endif
#endif

// ---------------- init padded cursors: cursor[b*CSTRIDE] = b*SLOT ----------------
__global__ __launch_bounds__(256) void init_cursor(int* __restrict__ cursor) {
  int i = blockIdx.x * blockDim.x + threadIdx.x;
  if (i < NBKT) cursor[i * CSTRIDE] = i * SLOT;
}

// ---------------- fused gemm (f32 in via reg-staged cvt, f16 MFMA) + scatter ----------------
// blocks [0,380): GEMM  H = z @ W1half^T (+b1 for drug panel), output f16
// blocks [380,380+NSCAT): LDS-aggregated bucket scatter of edges
#define BM 128
#define BN 128
#define BK 32

__global__ __launch_bounds__(256) void gemm_scatter(
    const float* __restrict__ z_drug, const float* __restrict__ z_react,
    const float* __restrict__ W1,     // (512 out) x (1024 in): [o][0:512]=L, [o][512:1024]=R
    const float* __restrict__ bias,
    const int* __restrict__ row, const int* __restrict__ col,
    _Float16* __restrict__ Hd, _Float16* __restrict__ Hr,
    int* __restrict__ cursor, uint64_t* __restrict__ pk)
{
  __shared__ _Float16 As[BM * BK];   // 8 KB (f16: 64B row stride, conflict-free frags)
  __shared__ _Float16 Bs[BN * BK];   // 8 KB
  __shared__ int lhist[NBKT];
  __shared__ int lbase[NBKT];

  const int bid = blockIdx.x;
  const int tid = threadIdx.x;

  if (bid >= GEMMBLKS) {
    // ---- scatter branch: block handles edges [e0, e1)
    const int sb = bid - GEMMBLKS;
    const int e0 = sb * EPB;
    const int e1 = (e0 + EPB < NEDGE) ? e0 + EPB : NEDGE;
    for (int i = tid; i < NBKT; i += 256) lhist[i] = 0;
    __syncthreads();
    for (int e = e0 + tid; e < e1; e += 256)
      atomicAdd(&lhist[col[e] >> 5], 1);
    __syncthreads();
    for (int i = tid; i < NBKT; i += 256) {
      int cnt = lhist[i];
      lbase[i] = cnt ? atomicAdd(&cursor[i * CSTRIDE], cnt) : 0;  // reserve range (padded line)
      lhist[i] = 0;                                               // reuse as local offset
    }
    __syncthreads();
    for (int e = e0 + tid; e < e1; e += 256) {
      int c = col[e];
      int r = row[e];
      int bkt = c >> 5;
      int lo = atomicAdd(&lhist[bkt], 1);
      pk[lbase[bkt] + lo] = ((uint64_t)e << 25) | ((uint64_t)r << 14) | (uint64_t)c;
    }
    return;
  }

  // ---- gemm branch: flat [0,64) -> drug (16 mb x 4 nb), [64,380) -> reaction (79 mb x 4 nb)
  const int z = (bid >= 64) ? 1 : 0;
  const int t = z ? bid - 64 : bid;
  const int mb = t >> 2;
  const int nb = t & 3;
  const int M = (z == 0) ? NDRUG : NREACT;
  const float* A = (z == 0) ? z_drug : z_react;
  const int boff = (z == 0) ? 0 : HIDDEN;      // left half for drug, right half for reaction
  _Float16* C = (z == 0) ? Hd : Hr;
  const bool has_bias = (z == 0);
  const int K = HIDDEN, N = HIDDEN;

  const int lane = tid & 63;
  const int wid = tid >> 6;
  const int wm = wid >> 1;
  const int wn = wid & 1;

  f32x4 acc[4][4];
#pragma unroll
  for (int i = 0; i < 4; ++i)
#pragma unroll
    for (int j = 0; j < 4; ++j) acc[i][j] = (f32x4){0.f, 0.f, 0.f, 0.f};

  const int row0 = mb * BM;
  const int col0 = nb * BN;
  // staging unit: u in [0,512): r = u>>2 (tile row), q = u&3 (8-elem col group)
  const int r0 = tid >> 2;          // unit half 0 row
  const int q0 = tid & 3;

  for (int kt = 0; kt < K; kt += BK) {
    // load f32 -> cvt f16 in regs (before barrier; global loads independent of LDS)
    f16x8 afh[2], bfh[2];
#pragma unroll
    for (int half = 0; half < 2; ++half) {
      const int r = r0 + half * 64;
      const int q = q0;
      int rA = row0 + r; rA = rA < M ? rA : M - 1;    // clamp for ragged M
      f32x8 va = *reinterpret_cast<const f32x8*>(A + (size_t)rA * K + kt + q * 8);
      afh[half] = __builtin_convertvector(va, f16x8);
      int rB = col0 + r;                               // N=512, exact
      f32x8 vb = *reinterpret_cast<const f32x8*>(W1 + (size_t)rB * (2 * HIDDEN) + boff + kt + q * 8);
      bfh[half] = __builtin_convertvector(vb, f16x8);
    }
    __syncthreads();   // previous iteration's fragment reads complete
#pragma unroll
    for (int half = 0; half < 2; ++half) {
      const int r = r0 + half * 64;
      *reinterpret_cast<f16x8*>(As + r * BK + q0 * 8) = afh[half];
      *reinterpret_cast<f16x8*>(Bs + r * BK + q0 * 8) = bfh[half];
    }
    __syncthreads();

    const int fr = lane & 15;
    const int kg = (lane >> 4) * 8;
    f16x8 af[4], bfr[4];
#pragma unroll
    for (int mi = 0; mi < 4; ++mi)
      af[mi] = *reinterpret_cast<const f16x8*>(As + (wm * 64 + mi * 16 + fr) * BK + kg);
#pragma unroll
    for (int ni = 0; ni < 4; ++ni)
      bfr[ni] = *reinterpret_cast<const f16x8*>(Bs + (wn * 64 + ni * 16 + fr) * BK + kg);
#pragma unroll
    for (int mi = 0; mi < 4; ++mi)
#pragma unroll
      for (int ni = 0; ni < 4; ++ni)
        acc[mi][ni] = __builtin_amdgcn_mfma_f32_16x16x32_f16(af[mi], bfr[ni], acc[mi][ni], 0, 0, 0);
  }

  const int crow = (lane >> 4) * 4;
  const int ccol = lane & 15;
#pragma unroll
  for (int ni = 0; ni < 4; ++ni) {
    const int gc = col0 + wn * 64 + ni * 16 + ccol;
    const float bv = has_bias ? bias[gc] : 0.0f;
#pragma unroll
    for (int mi = 0; mi < 4; ++mi) {
#pragma unroll
      for (int j = 0; j < 4; ++j) {
        const int gr = row0 + wm * 64 + mi * 16 + crow + j;
        if (gr < M) C[(size_t)gr * N + gc] = (_Float16)(acc[mi][ni][j] + bv);
      }
    }
  }
}

// ---------------- edge kernel: 512 thr, in-LDS col sort, Hr in LDS, static quad map ----
__global__ __launch_bounds__(ETHREADS) void edge_kernel(
    const _Float16* __restrict__ Hd, const _Float16* __restrict__ Hr,
    const uint64_t* __restrict__ pk, const int* __restrict__ cursor,
    const float* __restrict__ W2, const float* __restrict__ b2,
    float* __restrict__ out)
{
  __shared__ _Float16 hrs[32 * HRSTRIDE];     // 33.3 KB: the bucket's 32 Hr rows (padded)
  __shared__ uint64_t raw[MAXSL];             // 8 KB
  __shared__ uint64_t spk[MAXSL];             // 8 KB col-sorted
  __shared__ int qdesc[MAXSL / 4 + 32];       // quad descriptors
  __shared__ int cnt[32], cb[32], cnt2[32], qoff[32];
  __shared__ int nqs;

  // bucket->XCD chunked mapping: XCD x owns buckets [x*40, x*40+40)
  const int bid = blockIdx.x;
  const int xcd = bid & 7;
  const int idx = bid >> 3;                 // 0..79
  const int bucket = xcd * 40 + (idx >> 1);
  const int slice = idx & 1;
  const int base = bucket * SLOT;
  const int count = cursor[bucket * CSTRIDE] - base;   // pre-biased cursor
  const int per = (count + BPB2 - 1) / BPB2;
  const int s = slice * per;
  const int e_end0 = (s + per < count) ? s + per : count;
  const int n = (e_end0 > s) ? e_end0 - s : 0;

  const int tid = threadIdx.x;
  const int lane = tid & 63;
  const int li = lane & 15;
  const int wv = tid >> 6;                  // 0..7
  const int gid = wv * 4 + (lane >> 4);     // 0..31: static group id

  // ---- issue Hr preload: wave wv loads rows [wv*4, wv*4+4), one global_load_lds per row
#pragma unroll
  for (int rr2 = 0; rr2 < 4; ++rr2) {
    int rr = wv * 4 + rr2;
    int gr = bucket * 32 + rr;
    gr = (gr < NREACT) ? gr : NREACT - 1;   // clamp (empty tail buckets)
    const _Float16* src = Hr + (size_t)gr * HIDDEN + lane * 8;
    _Float16* dst = hrs + rr * HRSTRIDE;    // 1040B row stride, 16B aligned
    __builtin_amdgcn_global_load_lds(
        (const __attribute__((address_space(1))) void*)src,
        (__attribute__((address_space(3))) void*)dst, 16, 0, 0);
  }

  // ---- W2 fragment (global, L2-hot): lane covers elems li*8 + 128k
  f16x8 w2v[4];
#pragma unroll
  for (int k = 0; k < 4; ++k) {
    const float* p = W2 + li * 8 + k * 128;
    f16x8 q;
#pragma unroll
    for (int j = 0; j < 8; ++j) q[j] = (_Float16)p[j];
    w2v[k] = q;
  }
  const float bias2 = *b2;
  const f16x8 zero8 = (f16x8)(_Float16)0;

  // ---- in-LDS counting sort by local col (c & 31)
  if (tid < 32) { cnt[tid] = 0; cnt2[tid] = 0; }
  __syncthreads();
  for (int i = tid; i < n; i += ETHREADS) {
    uint64_t p = pk[base + s + i];
    raw[i] = p;
    atomicAdd(&cnt[(int)(p & 31)], 1);
  }
  __syncthreads();
  if (tid == 0) {
    int acc = 0, qa = 0;
    for (int j = 0; j < 32; ++j) {
      cb[j] = acc; acc += cnt[j];
      qoff[j] = qa; qa += (cnt[j] + 3) >> 2;
    }
    nqs = qa;
  }
  __syncthreads();
  for (int i = tid; i < n; i += ETHREADS) {
    uint64_t p = raw[i];
    int lc = (int)(p & 31);
    int lo = atomicAdd(&cnt2[lc], 1);
    spk[cb[lc] + lo] = p;
  }
  __syncthreads();
  if (tid < 32) {
    int j = tid, st = cb[j], len = cnt[j], o = qoff[j];
    for (int q = 0; q < len; q += 4) {
      int cn = len - q; cn = (cn < 4) ? cn : 4;
      qdesc[o++] = j | ((st + q) << 5) | (cn << 16);
    }
  }
  __syncthreads();   // also drains vmcnt -> hrs ready

  // ---- process quads, statically strided: group gid takes quads gid, gid+32, ...
  const int nq = nqs;
  for (int q = gid; q < nq; q += 32) {
    const int d = qdesc[q];
    const int lc = d & 31;
    const int st = (d >> 5) & 2047;
    const int cn = (d >> 16) & 7;

    const _Float16* hd[4];
    int si[4];
#pragma unroll
    for (int j = 0; j < 4; ++j) {
      int jj = (j < cn) ? j : cn - 1;
      uint64_t p = spk[st + jj];
      si[j] = (int)(p >> 25);
      hd[j] = Hd + (size_t)((p >> 14) & 0x7FF) * HIDDEN;
    }

    // prefetch the whole quad working set: 4 edges x 4 k-steps
    f16x8 vd[4][4];
#pragma unroll
    for (int j = 0; j < 4; ++j)
#pragma unroll
      for (int k = 0; k < 4; ++k)
        vd[j][k] = *reinterpret_cast<const f16x8*>(hd[j] + li * 8 + k * 128);

    // hr fragment from LDS (shared by the quad's 4 edges)
    f16x8 hv[4];
#pragma unroll
    for (int k = 0; k < 4; ++k)
      hv[k] = *reinterpret_cast<const f16x8*>(hrs + lc * HRSTRIDE + li * 8 + k * 128);

    float acc[4] = {0.f, 0.f, 0.f, 0.f};
#pragma unroll
    for (int j = 0; j < 4; ++j) {
#pragma unroll
      for (int k = 0; k < 4; ++k) {
        f16x8 t = __builtin_elementwise_max(vd[j][k] + hv[k], zero8);
#if defined(HAVE_FDOT2)
#pragma unroll
        for (int qq = 0; qq < 4; ++qq) {
          f16x2 wp = {w2v[k][2 * qq], w2v[k][2 * qq + 1]};
          f16x2 sp = {t[2 * qq], t[2 * qq + 1]};
          acc[j] = __builtin_amdgcn_fdot2(sp, wp, acc[j], false);
        }
#else
#pragma unroll
        for (int qq = 0; qq < 8; ++qq)
          acc[j] += (float)t[qq] * (float)w2v[k][qq];
#endif
      }
    }
#pragma unroll
    for (int off = 8; off >= 1; off >>= 1) {
#pragma unroll
      for (int j = 0; j < 4; ++j) acc[j] += __shfl_xor(acc[j], off);
    }
    if (li == 0) {
      for (int j = 0; j < cn; ++j) out[si[j]] = acc[j] + bias2;
    }
  }
}

extern "C" void kernel_launch(void* const* d_in, const int* in_sizes, int n_in,
                              void* d_out, int out_size, void* d_ws, size_t ws_size,
                              hipStream_t stream) {
  const float* z_drug  = (const float*)d_in[0];
  const float* z_react = (const float*)d_in[1];
  const int*   row     = (const int*)d_in[2];
  const int*   col     = (const int*)d_in[3];
  const float* W1      = (const float*)d_in[4];
  const float* b1      = (const float*)d_in[5];
  const float* W2      = (const float*)d_in[6];
  const float* b2      = (const float*)d_in[7];
  float* out = (float*)d_out;

  char* ws = (char*)d_ws;
  size_t off = 0;
  auto alloc = [&](size_t bytes) {
    void* p = ws + off;
    off += (bytes + 255) & ~(size_t)255;
    return p;
  };
  _Float16* Hd   = (_Float16*)alloc((size_t)NDRUG * HIDDEN * 2);
  _Float16* Hr   = (_Float16*)alloc((size_t)NREACT * HIDDEN * 2);
  int*      cursor = (int*)alloc((size_t)NBKT * CSTRIDE * 4);       // 20 KB padded
  uint64_t* pk     = (uint64_t*)alloc((size_t)NBKT * SLOT * 8);     // 5.2 MB

  init_cursor<<<2, 256, 0, stream>>>(cursor);
  gemm_scatter<<<GEMMBLKS + NSCAT, 256, 0, stream>>>(z_drug, z_react, W1, b1,
                                                     row, col, Hd, Hr, cursor, pk);
  edge_kernel<<<EBLK, ETHREADS, 0, stream>>>(Hd, Hr, pk, cursor, W2, b2, out);
}

// Round 12
// 68.834 us; speedup vs baseline: 1.1097x; 1.0201x over previous
//
#include <hip/hip_runtime.h>
#include <stdint.h>

#define HIDDEN 512
#define NDRUG 2000
#define NREACT 10000
#define NEDGE 400000

// bucketed near-sort: 313 used buckets x 32 cols each (c>>5), padded to 320
#define NBKT 320
#define SLOT 2048                 // capacity per bucket (mean ~1280, sigma ~36; +21 sigma)
#define CSTRIDE 16                // cursor padded to 1 int per 64B cache line
#define NSCAT 128                 // scatter blocks (LDS-aggregated)
#define EPB ((NEDGE + NSCAT - 1) / NSCAT)   // 3125 edges per scatter block

// edge kernel: 4 blocks per bucket, 512 threads, in-LDS col sort + Hr in LDS
#define BPB2 4
#define EBLK (NBKT * BPB2)        // 1280
#define MAXSL 512                 // max slice entries = ceil(SLOT/BPB2)
#define HRSTRIDE 520              // f16 elems per LDS hr row (512 + 8 pad)
#define ETHREADS 512

#define GEMMBLKS 380              // gemm blocks in fused gemm_scatter grid

typedef __attribute__((ext_vector_type(8))) _Float16 f16x8;
typedef __attribute__((ext_vector_type(2))) _Float16 f16x2;
typedef __attribute__((ext_vector_type(4))) float f32x4;
typedef __attribute__((ext_vector_type(8))) float f32x8;
typedef __attribute__((ext_vector_type(4))) float float4v;
typedef __attribute__((ext_vector_type(4))) _Float16 f16x4;

#if defined(__has_builtin)
#if __has_builtin(__builtin_amdgcn_fdot2)
#define HAVE_FDOT2 1
#endif
#endif

// ---------------- w1prep: split W1 into f16 halves + init cursors ----------------
// blocks [0,128): W1 split; blocks [128,130): cursor init
__global__ __launch_bounds__(256) void w1prep(const float* __restrict__ W1,
                                              _Float16* __restrict__ WL,
                                              _Float16* __restrict__ WR,
                                              int* __restrict__ cursor) {
  const int b = blockIdx.x;
  const int tid = threadIdx.x;
  if (b < 128) {
    const int nth = 128 * 256;
    const int NQ = HIDDEN * 2 * HIDDEN / 4;   // 131072 quads
    for (int i = b * 256 + tid; i < NQ; i += nth) {
      int e = i * 4;
      int o = e >> 10, j = e & 1023;
      float4v v = *reinterpret_cast<const float4v*>(W1 + e);
      f16x4 q; q[0]=(_Float16)v[0]; q[1]=(_Float16)v[1]; q[2]=(_Float16)v[2]; q[3]=(_Float16)v[3];
      if (j < HIDDEN) *reinterpret_cast<f16x4*>(WL + o * HIDDEN + j) = q;
      else            *reinterpret_cast<f16x4*>(WR + o * HIDDEN + (j - HIDDEN)) = q;
    }
  } else {
    int i = (b - 128) * 256 + tid;
    if (i < NBKT) cursor[i * CSTRIDE] = i * SLOT;
  }
}

// ---------------- fused gemm (A: f32 reg-staged; B: f16 gload_lds) + scatter ----------------
// blocks [0,380): GEMM  H = z @ W1half^T (+b1 for drug panel), output f16
// blocks [380,380+NSCAT): LDS-aggregated bucket scatter of edges
#define BM 128
#define BN 128
#define BK 32

__global__ __launch_bounds__(256) void gemm_scatter(
    const float* __restrict__ z_drug, const float* __restrict__ z_react,
    const _Float16* __restrict__ BL, const _Float16* __restrict__ BR,
    const float* __restrict__ bias,
    const int* __restrict__ row, const int* __restrict__ col,
    _Float16* __restrict__ Hd, _Float16* __restrict__ Hr,
    int* __restrict__ cursor, uint64_t* __restrict__ pk)
{
  __shared__ _Float16 As[BM * BK];   // 8 KB f16 (64B row stride, conflict-free frags)
  __shared__ _Float16 Bs[BN * BK];   // 8 KB
  __shared__ int lhist[NBKT];
  __shared__ int lbase[NBKT];

  const int bid = blockIdx.x;
  const int tid = threadIdx.x;

  if (bid >= GEMMBLKS) {
    // ---- scatter branch: block handles edges [e0, e1)
    const int sb = bid - GEMMBLKS;
    const int e0 = sb * EPB;
    const int e1 = (e0 + EPB < NEDGE) ? e0 + EPB : NEDGE;
    for (int i = tid; i < NBKT; i += 256) lhist[i] = 0;
    __syncthreads();
    for (int e = e0 + tid; e < e1; e += 256)
      atomicAdd(&lhist[col[e] >> 5], 1);
    __syncthreads();
    for (int i = tid; i < NBKT; i += 256) {
      int cnt = lhist[i];
      lbase[i] = cnt ? atomicAdd(&cursor[i * CSTRIDE], cnt) : 0;  // reserve range (padded line)
      lhist[i] = 0;                                               // reuse as local offset
    }
    __syncthreads();
    for (int e = e0 + tid; e < e1; e += 256) {
      int c = col[e];
      int r = row[e];
      int bkt = c >> 5;
      int lo = atomicAdd(&lhist[bkt], 1);
      pk[lbase[bkt] + lo] = ((uint64_t)e << 25) | ((uint64_t)r << 14) | (uint64_t)c;
    }
    return;
  }

  // ---- gemm branch: flat [0,64) -> drug (16 mb x 4 nb), [64,380) -> reaction (79 mb x 4 nb)
  const int z = (bid >= 64) ? 1 : 0;
  const int t = z ? bid - 64 : bid;
  const int mb = t >> 2;
  const int nb = t & 3;
  const int M = (z == 0) ? NDRUG : NREACT;
  const float* A = (z == 0) ? z_drug : z_react;
  const _Float16* B = (z == 0) ? BL : BR;
  _Float16* C = (z == 0) ? Hd : Hr;
  const bool has_bias = (z == 0);
  const int K = HIDDEN, N = HIDDEN;

  const int lane = tid & 63;
  const int wid = tid >> 6;
  const int wm = wid >> 1;
  const int wn = wid & 1;

  f32x4 acc[4][4];
#pragma unroll
  for (int i = 0; i < 4; ++i)
#pragma unroll
    for (int j = 0; j < 4; ++j) acc[i][j] = (f32x4){0.f, 0.f, 0.f, 0.f};

  const int row0 = mb * BM;
  const int col0 = nb * BN;
  // A staging unit: tid -> (r0 = tid>>2 in [0,64), q0 = tid&3 -> 8-f32 col group)
  const int r0 = tid >> 2;
  const int q0 = tid & 3;
  // B staging (gload_lds, f16): wave-uniform base + lane*16B
  const int srow = lane >> 2;           // 0..15
  const int scol = (lane & 3) * 8;      // f16 col in 32-wide row

  for (int kt = 0; kt < K; kt += BK) {
    // A: load f32 -> cvt f16 in regs (issued before barrier, global only)
    f16x8 afh[2];
#pragma unroll
    for (int half = 0; half < 2; ++half) {
      int rA = row0 + r0 + half * 64;
      rA = rA < M ? rA : M - 1;                       // clamp for ragged M
      f32x8 va = *reinterpret_cast<const f32x8*>(A + (size_t)rA * K + kt + q0 * 8);
      afh[half] = __builtin_convertvector(va, f16x8);
    }
    __syncthreads();   // previous iteration's fragment reads complete
#pragma unroll
    for (int half = 0; half < 2; ++half)
      *reinterpret_cast<f16x8*>(As + (r0 + half * 64) * BK + q0 * 8) = afh[half];
    // B: f16 async global->LDS (2 calls/wave)
#pragma unroll
    for (int i = 0; i < 2; ++i) {
      int rB = col0 + wid * 32 + i * 16 + srow;       // N=512, exact
      const _Float16* gB = B + (size_t)rB * K + kt + scol;
      _Float16* lB = Bs + (wid * 32 + i * 16) * BK;
      __builtin_amdgcn_global_load_lds(
          (const __attribute__((address_space(1))) void*)gB,
          (__attribute__((address_space(3))) void*)lB, 16, 0, 0);
    }
    __syncthreads();   // drains lgkm (ds_write) + vmcnt (gload_lds)

    const int fr = lane & 15;
    const int kg = (lane >> 4) * 8;
    f16x8 af[4], bfr[4];
#pragma unroll
    for (int mi = 0; mi < 4; ++mi)
      af[mi] = *reinterpret_cast<const f16x8*>(As + (wm * 64 + mi * 16 + fr) * BK + kg);
#pragma unroll
    for (int ni = 0; ni < 4; ++ni)
      bfr[ni] = *reinterpret_cast<const f16x8*>(Bs + (wn * 64 + ni * 16 + fr) * BK + kg);
#pragma unroll
    for (int mi = 0; mi < 4; ++mi)
#pragma unroll
      for (int ni = 0; ni < 4; ++ni)
        acc[mi][ni] = __builtin_amdgcn_mfma_f32_16x16x32_f16(af[mi], bfr[ni], acc[mi][ni], 0, 0, 0);
  }

  const int crow = (lane >> 4) * 4;
  const int ccol = lane & 15;
#pragma unroll
  for (int ni = 0; ni < 4; ++ni) {
    const int gc = col0 + wn * 64 + ni * 16 + ccol;
    const float bv = has_bias ? bias[gc] : 0.0f;
#pragma unroll
    for (int mi = 0; mi < 4; ++mi) {
#pragma unroll
      for (int j = 0; j < 4; ++j) {
        const int gr = row0 + wm * 64 + mi * 16 + crow + j;
        if (gr < M) C[(size_t)gr * N + gc] = (_Float16)(acc[mi][ni][j] + bv);
      }
    }
  }
}

// ---------------- edge kernel: 512 thr, 4 blocks/bucket, in-LDS col sort, Hr in LDS ----
__global__ __launch_bounds__(ETHREADS) void edge_kernel(
    const _Float16* __restrict__ Hd, const _Float16* __restrict__ Hr,
    const uint64_t* __restrict__ pk, const int* __restrict__ cursor,
    const float* __restrict__ W2, const float* __restrict__ b2,
    float* __restrict__ out)
{
  __shared__ _Float16 hrs[32 * HRSTRIDE];     // 33.3 KB: the bucket's 32 Hr rows (padded)
  __shared__ uint64_t raw[MAXSL];             // 4 KB
  __shared__ uint64_t spk[MAXSL];             // 4 KB col-sorted
  __shared__ int qdesc[MAXSL / 4 + 32];       // quad descriptors
  __shared__ int cnt[32], cb[32], cnt2[32], qoff[32];
  __shared__ int nqs;

  // bucket->XCD chunked mapping: XCD x owns buckets [x*40, x*40+40)
  const int bid = blockIdx.x;
  const int xcd = bid & 7;
  const int idx = bid >> 3;                 // 0..159
  const int bucket = xcd * 40 + (idx >> 2);
  const int slice = idx & 3;
  const int base = bucket * SLOT;
  const int count = cursor[bucket * CSTRIDE] - base;   // pre-biased cursor
  const int per = (count + BPB2 - 1) / BPB2;
  const int s = slice * per;
  const int e_end0 = (s + per < count) ? s + per : count;
  const int n = (e_end0 > s) ? e_end0 - s : 0;

  const int tid = threadIdx.x;
  const int lane = tid & 63;
  const int li = lane & 15;
  const int wv = tid >> 6;                  // 0..7
  const int gid = wv * 4 + (lane >> 4);     // 0..31: static group id

  // ---- issue Hr preload: wave wv loads rows [wv*4, wv*4+4), one global_load_lds per row
#pragma unroll
  for (int rr2 = 0; rr2 < 4; ++rr2) {
    int rr = wv * 4 + rr2;
    int gr = bucket * 32 + rr;
    gr = (gr < NREACT) ? gr : NREACT - 1;   // clamp (empty tail buckets)
    const _Float16* src = Hr + (size_t)gr * HIDDEN + lane * 8;
    _Float16* dst = hrs + rr * HRSTRIDE;    // 1040B row stride, 16B aligned
    __builtin_amdgcn_global_load_lds(
        (const __attribute__((address_space(1))) void*)src,
        (__attribute__((address_space(3))) void*)dst, 16, 0, 0);
  }

  // ---- W2 fragment (global, L2-hot): lane covers elems li*8 + 128k
  f16x8 w2v[4];
#pragma unroll
  for (int k = 0; k < 4; ++k) {
    const float* p = W2 + li * 8 + k * 128;
    f16x8 q;
#pragma unroll
    for (int j = 0; j < 8; ++j) q[j] = (_Float16)p[j];
    w2v[k] = q;
  }
  const float bias2 = *b2;
  const f16x8 zero8 = (f16x8)(_Float16)0;

  // ---- in-LDS counting sort by local col (c & 31)
  if (tid < 32) { cnt[tid] = 0; cnt2[tid] = 0; }
  __syncthreads();
  for (int i = tid; i < n; i += ETHREADS) {
    uint64_t p = pk[base + s + i];
    raw[i] = p;
    atomicAdd(&cnt[(int)(p & 31)], 1);
  }
  __syncthreads();
  if (tid == 0) {
    int acc = 0, qa = 0;
    for (int j = 0; j < 32; ++j) {
      cb[j] = acc; acc += cnt[j];
      qoff[j] = qa; qa += (cnt[j] + 3) >> 2;
    }
    nqs = qa;
  }
  __syncthreads();
  for (int i = tid; i < n; i += ETHREADS) {
    uint64_t p = raw[i];
    int lc = (int)(p & 31);
    int lo = atomicAdd(&cnt2[lc], 1);
    spk[cb[lc] + lo] = p;
  }
  __syncthreads();
  if (tid < 32) {
    int j = tid, st = cb[j], len = cnt[j], o = qoff[j];
    for (int q = 0; q < len; q += 4) {
      int cn = len - q; cn = (cn < 4) ? cn : 4;
      qdesc[o++] = j | ((st + q) << 5) | (cn << 16);
    }
  }
  __syncthreads();   // also drains vmcnt -> hrs ready

  // ---- process quads, statically strided: group gid takes quads gid, gid+32, ...
  const int nq = nqs;
  for (int q = gid; q < nq; q += 32) {
    const int d = qdesc[q];
    const int lc = d & 31;
    const int st = (d >> 5) & 511;
    const int cn = (d >> 16) & 7;

    const _Float16* hd[4];
    int si[4];
#pragma unroll
    for (int j = 0; j < 4; ++j) {
      int jj = (j < cn) ? j : cn - 1;
      uint64_t p = spk[st + jj];
      si[j] = (int)(p >> 25);
      hd[j] = Hd + (size_t)((p >> 14) & 0x7FF) * HIDDEN;
    }

    // prefetch the whole quad working set: 4 edges x 4 k-steps
    f16x8 vd[4][4];
#pragma unroll
    for (int j = 0; j < 4; ++j)
#pragma unroll
      for (int k = 0; k < 4; ++k)
        vd[j][k] = *reinterpret_cast<const f16x8*>(hd[j] + li * 8 + k * 128);

    // hr fragment from LDS (shared by the quad's 4 edges)
    f16x8 hv[4];
#pragma unroll
    for (int k = 0; k < 4; ++k)
      hv[k] = *reinterpret_cast<const f16x8*>(hrs + lc * HRSTRIDE + li * 8 + k * 128);

    float acc[4] = {0.f, 0.f, 0.f, 0.f};
#pragma unroll
    for (int j = 0; j < 4; ++j) {
#pragma unroll
      for (int k = 0; k < 4; ++k) {
        f16x8 t = __builtin_elementwise_max(vd[j][k] + hv[k], zero8);
#if defined(HAVE_FDOT2)
#pragma unroll
        for (int qq = 0; qq < 4; ++qq) {
          f16x2 wp = {w2v[k][2 * qq], w2v[k][2 * qq + 1]};
          f16x2 sp = {t[2 * qq], t[2 * qq + 1]};
          acc[j] = __builtin_amdgcn_fdot2(sp, wp, acc[j], false);
        }
#else
#pragma unroll
        for (int qq = 0; qq < 8; ++qq)
          acc[j] += (float)t[qq] * (float)w2v[k][qq];
#endif
      }
    }
#pragma unroll
    for (int off = 8; off >= 1; off >>= 1) {
#pragma unroll
      for (int j = 0; j < 4; ++j) acc[j] += __shfl_xor(acc[j], off);
    }
    if (li == 0) {
      for (int j = 0; j < cn; ++j) out[si[j]] = acc[j] + bias2;
    }
  }
}

extern "C" void kernel_launch(void* const* d_in, const int* in_sizes, int n_in,
                              void* d_out, int out_size, void* d_ws, size_t ws_size,
                              hipStream_t stream) {
  const float* z_drug  = (const float*)d_in[0];
  const float* z_react = (const float*)d_in[1];
  const int*   row     = (const int*)d_in[2];
  const int*   col     = (const int*)d_in[3];
  const float* W1      = (const float*)d_in[4];
  const float* b1      = (const float*)d_in[5];
  const float* W2      = (const float*)d_in[6];
  const float* b2      = (const float*)d_in[7];
  float* out = (float*)d_out;

  char* ws = (char*)d_ws;
  size_t off = 0;
  auto alloc = [&](size_t bytes) {
    void* p = ws + off;
    off += (bytes + 255) & ~(size_t)255;
    return p;
  };
  _Float16* wl_f = (_Float16*)alloc((size_t)HIDDEN * HIDDEN * 2);
  _Float16* wr_f = (_Float16*)alloc((size_t)HIDDEN * HIDDEN * 2);
  _Float16* Hd   = (_Float16*)alloc((size_t)NDRUG * HIDDEN * 2);
  _Float16* Hr   = (_Float16*)alloc((size_t)NREACT * HIDDEN * 2);
  int*      cursor = (int*)alloc((size_t)NBKT * CSTRIDE * 4);       // 20 KB padded
  uint64_t* pk     = (uint64_t*)alloc((size_t)NBKT * SLOT * 8);     // 5.2 MB

  w1prep<<<130, 256, 0, stream>>>(W1, wl_f, wr_f, cursor);
  gemm_scatter<<<GEMMBLKS + NSCAT, 256, 0, stream>>>(z_drug, z_react, wl_f, wr_f, b1,
                                                     row, col, Hd, Hr, cursor, pk);
  edge_kernel<<<EBLK, ETHREADS, 0, stream>>>(Hd, Hr, pk, cursor, W2, b2, out);
}

// Round 13
// 67.408 us; speedup vs baseline: 1.1332x; 1.0212x over previous
//
#include <hip/hip_runtime.h>
#include <stdint.h>

#define HIDDEN 512
#define NDRUG 2000
#define NREACT 10000
#define NEDGE 400000

// bucketed near-sort: 313 used buckets x 32 cols each (c>>5), padded to 320
#define NBKT 320
#define SLOT 2048                 // capacity per bucket (mean ~1280, sigma ~36; +21 sigma)
#define CSTRIDE 16                // cursor padded to 1 int per 64B cache line
#define NSCAT 128                 // scatter blocks (LDS-aggregated)
#define EPB ((NEDGE + NSCAT - 1) / NSCAT)   // 3125 edges per scatter block

// edge kernel: 2 blocks per bucket, 512 threads, in-LDS col sort + Hr in LDS
#define BPB2 2
#define EBLK (NBKT * BPB2)        // 640
#define MAXSL 1024                // max slice entries = ceil(SLOT/BPB2)
#define HRSTRIDE 520              // f16 elems per LDS hr row (512 + 8 pad)
#define ETHREADS 512

typedef __attribute__((ext_vector_type(8))) _Float16 f16x8;
typedef __attribute__((ext_vector_type(2))) _Float16 f16x2;
typedef __attribute__((ext_vector_type(4))) float f32x4;
typedef __attribute__((ext_vector_type(8))) float f32x8;
typedef __attribute__((ext_vector_type(4))) float float4v;
typedef __attribute__((ext_vector_type(4))) _Float16 f16x4;

#if defined(__has_builtin)
#if __has_builtin(__builtin_amdgcn_fdot2)
#define HAVE_FDOT2 1
#endif
#endif

// ---------------- w1prep: split W1 into f16 halves + init cursors ----------------
// blocks [0,128): W1 split; blocks [128,130): cursor init
__global__ __launch_bounds__(256) void w1prep(const float* __restrict__ W1,
                                              _Float16* __restrict__ WL,
                                              _Float16* __restrict__ WR,
                                              int* __restrict__ cursor) {
  const int b = blockIdx.x;
  const int tid = threadIdx.x;
  if (b < 128) {
    const int nth = 128 * 256;
    const int NQ = HIDDEN * 2 * HIDDEN / 4;   // 131072 quads
    for (int i = b * 256 + tid; i < NQ; i += nth) {
      int e = i * 4;
      int o = e >> 10, j = e & 1023;
      float4v v = *reinterpret_cast<const float4v*>(W1 + e);
      f16x4 q; q[0]=(_Float16)v[0]; q[1]=(_Float16)v[1]; q[2]=(_Float16)v[2]; q[3]=(_Float16)v[3];
      if (j < HIDDEN) *reinterpret_cast<f16x4*>(WL + o * HIDDEN + j) = q;
      else            *reinterpret_cast<f16x4*>(WR + o * HIDDEN + (j - HIDDEN)) = q;
    }
  } else {
    int i = (b - 128) * 256 + tid;
    if (i < NBKT) cursor[i * CSTRIDE] = i * SLOT;
  }
}

// ---------------- fused gemm (A: f32 reg-staged; B: f16 gload_lds) + scatter ----------------
// BM=64 tile: 756 gemm blocks (~3/CU) for latency hiding.
// blocks [0,128): drug (32 mb x 4 nb); [128,756): reaction (157 mb x 4 nb);
// blocks [756,756+NSCAT): LDS-aggregated bucket scatter of edges
#define BM 64
#define BN 128
#define BK 32
#define GEMMBLKS 756

__global__ __launch_bounds__(256) void gemm_scatter(
    const float* __restrict__ z_drug, const float* __restrict__ z_react,
    const _Float16* __restrict__ BL, const _Float16* __restrict__ BR,
    const float* __restrict__ bias,
    const int* __restrict__ row, const int* __restrict__ col,
    _Float16* __restrict__ Hd, _Float16* __restrict__ Hr,
    int* __restrict__ cursor, uint64_t* __restrict__ pk)
{
  __shared__ _Float16 As[BM * BK];   // 4 KB f16 (64B row stride, conflict-free frags)
  __shared__ _Float16 Bs[BN * BK];   // 8 KB
  __shared__ int lhist[NBKT];
  __shared__ int lbase[NBKT];

  const int bid = blockIdx.x;
  const int tid = threadIdx.x;

  if (bid >= GEMMBLKS) {
    // ---- scatter branch: block handles edges [e0, e1)
    const int sb = bid - GEMMBLKS;
    const int e0 = sb * EPB;
    const int e1 = (e0 + EPB < NEDGE) ? e0 + EPB : NEDGE;
    for (int i = tid; i < NBKT; i += 256) lhist[i] = 0;
    __syncthreads();
    for (int e = e0 + tid; e < e1; e += 256)
      atomicAdd(&lhist[col[e] >> 5], 1);
    __syncthreads();
    for (int i = tid; i < NBKT; i += 256) {
      int cnt = lhist[i];
      lbase[i] = cnt ? atomicAdd(&cursor[i * CSTRIDE], cnt) : 0;  // reserve range (padded line)
      lhist[i] = 0;                                               // reuse as local offset
    }
    __syncthreads();
    for (int e = e0 + tid; e < e1; e += 256) {
      int c = col[e];
      int r = row[e];
      int bkt = c >> 5;
      int lo = atomicAdd(&lhist[bkt], 1);
      pk[lbase[bkt] + lo] = ((uint64_t)e << 25) | ((uint64_t)r << 14) | (uint64_t)c;
    }
    return;
  }

  // ---- gemm branch
  const int z = (bid >= 128) ? 1 : 0;
  const int t = z ? bid - 128 : bid;
  const int mb = t >> 2;
  const int nb = t & 3;
  const int M = (z == 0) ? NDRUG : NREACT;
  const float* A = (z == 0) ? z_drug : z_react;
  const _Float16* B = (z == 0) ? BL : BR;
  _Float16* C = (z == 0) ? Hd : Hr;
  const bool has_bias = (z == 0);
  const int K = HIDDEN, N = HIDDEN;

  const int lane = tid & 63;
  const int wid = tid >> 6;     // 0..3 = wn (column wave); wm = 0 (all rows)
  const int wn = wid;

  f32x4 acc[4][2];
#pragma unroll
  for (int i = 0; i < 4; ++i)
#pragma unroll
    for (int j = 0; j < 2; ++j) acc[i][j] = (f32x4){0.f, 0.f, 0.f, 0.f};

  const int row0 = mb * BM;
  const int col0 = nb * BN;
  // A staging unit: tid -> (r0 = tid>>2 in [0,64), q0 = tid&3 -> 8-f32 col group)
  const int r0 = tid >> 2;
  const int q0 = tid & 3;
  // B staging (gload_lds, f16): wave-uniform base + lane*16B
  const int srow = lane >> 2;           // 0..15
  const int scol = (lane & 3) * 8;      // f16 col in 32-wide row

  for (int kt = 0; kt < K; kt += BK) {
    // A: load f32 -> cvt f16 in regs (issued before barrier, global only)
    int rA = row0 + r0;
    rA = rA < M ? rA : M - 1;                       // clamp for ragged M
    f32x8 va = *reinterpret_cast<const f32x8*>(A + (size_t)rA * K + kt + q0 * 8);
    f16x8 afh = __builtin_convertvector(va, f16x8);
    __syncthreads();   // previous iteration's fragment reads complete
    *reinterpret_cast<f16x8*>(As + r0 * BK + q0 * 8) = afh;
    // B: f16 async global->LDS (2 calls/wave)
#pragma unroll
    for (int i = 0; i < 2; ++i) {
      int rB = col0 + wid * 32 + i * 16 + srow;       // N=512, exact
      const _Float16* gB = B + (size_t)rB * K + kt + scol;
      _Float16* lB = Bs + (wid * 32 + i * 16) * BK;
      __builtin_amdgcn_global_load_lds(
          (const __attribute__((address_space(1))) void*)gB,
          (__attribute__((address_space(3))) void*)lB, 16, 0, 0);
    }
    __syncthreads();   // drains lgkm (ds_write) + vmcnt (gload_lds)

    const int fr = lane & 15;
    const int kg = (lane >> 4) * 8;
    f16x8 af[4], bfr[2];
#pragma unroll
    for (int mi = 0; mi < 4; ++mi)
      af[mi] = *reinterpret_cast<const f16x8*>(As + (mi * 16 + fr) * BK + kg);
#pragma unroll
    for (int ni = 0; ni < 2; ++ni)
      bfr[ni] = *reinterpret_cast<const f16x8*>(Bs + (wn * 32 + ni * 16 + fr) * BK + kg);
#pragma unroll
    for (int mi = 0; mi < 4; ++mi)
#pragma unroll
      for (int ni = 0; ni < 2; ++ni)
        acc[mi][ni] = __builtin_amdgcn_mfma_f32_16x16x32_f16(af[mi], bfr[ni], acc[mi][ni], 0, 0, 0);
  }

  const int crow = (lane >> 4) * 4;
  const int ccol = lane & 15;
#pragma unroll
  for (int ni = 0; ni < 2; ++ni) {
    const int gc = col0 + wn * 32 + ni * 16 + ccol;
    const float bv = has_bias ? bias[gc] : 0.0f;
#pragma unroll
    for (int mi = 0; mi < 4; ++mi) {
#pragma unroll
      for (int j = 0; j < 4; ++j) {
        const int gr = row0 + mi * 16 + crow + j;
        if (gr < M) C[(size_t)gr * N + gc] = (_Float16)(acc[mi][ni][j] + bv);
      }
    }
  }
}

// ---------------- edge kernel: 512 thr, 2 blocks/bucket, in-LDS col sort, Hr in LDS ----
__global__ __launch_bounds__(ETHREADS) void edge_kernel(
    const _Float16* __restrict__ Hd, const _Float16* __restrict__ Hr,
    const uint64_t* __restrict__ pk, const int* __restrict__ cursor,
    const float* __restrict__ W2, const float* __restrict__ b2,
    float* __restrict__ out)
{
  __shared__ _Float16 hrs[32 * HRSTRIDE];     // 33.3 KB: the bucket's 32 Hr rows (padded)
  __shared__ uint64_t raw[MAXSL];             // 8 KB
  __shared__ uint64_t spk[MAXSL];             // 8 KB col-sorted
  __shared__ int qdesc[MAXSL / 4 + 32];       // quad descriptors
  __shared__ int cnt[32], cb[32], cnt2[32], qoff[32];
  __shared__ int nqs;

  // bucket->XCD chunked mapping: XCD x owns buckets [x*40, x*40+40)
  const int bid = blockIdx.x;
  const int xcd = bid & 7;
  const int idx = bid >> 3;                 // 0..79
  const int bucket = xcd * 40 + (idx >> 1);
  const int slice = idx & 1;
  const int base = bucket * SLOT;
  const int count = cursor[bucket * CSTRIDE] - base;   // pre-biased cursor
  const int per = (count + BPB2 - 1) / BPB2;
  const int s = slice * per;
  const int e_end0 = (s + per < count) ? s + per : count;
  const int n = (e_end0 > s) ? e_end0 - s : 0;

  const int tid = threadIdx.x;
  const int lane = tid & 63;
  const int li = lane & 15;
  const int wv = tid >> 6;                  // 0..7
  const int gid = wv * 4 + (lane >> 4);     // 0..31: static group id

  // ---- issue Hr preload: wave wv loads rows [wv*4, wv*4+4), one global_load_lds per row
#pragma unroll
  for (int rr2 = 0; rr2 < 4; ++rr2) {
    int rr = wv * 4 + rr2;
    int gr = bucket * 32 + rr;
    gr = (gr < NREACT) ? gr : NREACT - 1;   // clamp (empty tail buckets)
    const _Float16* src = Hr + (size_t)gr * HIDDEN + lane * 8;
    _Float16* dst = hrs + rr * HRSTRIDE;    // 1040B row stride, 16B aligned
    __builtin_amdgcn_global_load_lds(
        (const __attribute__((address_space(1))) void*)src,
        (__attribute__((address_space(3))) void*)dst, 16, 0, 0);
  }

  // ---- W2 fragment (global, L2-hot): lane covers elems li*8 + 128k
  f16x8 w2v[4];
#pragma unroll
  for (int k = 0; k < 4; ++k) {
    const float* p = W2 + li * 8 + k * 128;
    f16x8 q;
#pragma unroll
    for (int j = 0; j < 8; ++j) q[j] = (_Float16)p[j];
    w2v[k] = q;
  }
  const float bias2 = *b2;
  const f16x8 zero8 = (f16x8)(_Float16)0;

  // ---- in-LDS counting sort by local col (c & 31)
  if (tid < 32) { cnt[tid] = 0; cnt2[tid] = 0; }
  __syncthreads();
  for (int i = tid; i < n; i += ETHREADS) {
    uint64_t p = pk[base + s + i];
    raw[i] = p;
    atomicAdd(&cnt[(int)(p & 31)], 1);
  }
  __syncthreads();
  if (tid == 0) {
    int acc = 0, qa = 0;
    for (int j = 0; j < 32; ++j) {
      cb[j] = acc; acc += cnt[j];
      qoff[j] = qa; qa += (cnt[j] + 3) >> 2;
    }
    nqs = qa;
  }
  __syncthreads();
  for (int i = tid; i < n; i += ETHREADS) {
    uint64_t p = raw[i];
    int lc = (int)(p & 31);
    int lo = atomicAdd(&cnt2[lc], 1);
    spk[cb[lc] + lo] = p;
  }
  __syncthreads();
  if (tid < 32) {
    int j = tid, st = cb[j], len = cnt[j], o = qoff[j];
    for (int q = 0; q < len; q += 4) {
      int cn = len - q; cn = (cn < 4) ? cn : 4;
      qdesc[o++] = j | ((st + q) << 5) | (cn << 16);
    }
  }
  __syncthreads();   // also drains vmcnt -> hrs ready

  // ---- process quads, statically strided: group gid takes quads gid, gid+32, ...
  const int nq = nqs;
  for (int q = gid; q < nq; q += 32) {
    const int d = qdesc[q];
    const int lc = d & 31;
    const int st = (d >> 5) & 2047;
    const int cn = (d >> 16) & 7;

    const _Float16* hd[4];
    int si[4];
#pragma unroll
    for (int j = 0; j < 4; ++j) {
      int jj = (j < cn) ? j : cn - 1;
      uint64_t p = spk[st + jj];
      si[j] = (int)(p >> 25);
      hd[j] = Hd + (size_t)((p >> 14) & 0x7FF) * HIDDEN;
    }

    // prefetch the whole quad working set: 4 edges x 4 k-steps
    f16x8 vd[4][4];
#pragma unroll
    for (int j = 0; j < 4; ++j)
#pragma unroll
      for (int k = 0; k < 4; ++k)
        vd[j][k] = *reinterpret_cast<const f16x8*>(hd[j] + li * 8 + k * 128);

    // hr fragment from LDS (shared by the quad's 4 edges)
    f16x8 hv[4];
#pragma unroll
    for (int k = 0; k < 4; ++k)
      hv[k] = *reinterpret_cast<const f16x8*>(hrs + lc * HRSTRIDE + li * 8 + k * 128);

    float acc[4] = {0.f, 0.f, 0.f, 0.f};
#pragma unroll
    for (int j = 0; j < 4; ++j) {
#pragma unroll
      for (int k = 0; k < 4; ++k) {
        f16x8 t = __builtin_elementwise_max(vd[j][k] + hv[k], zero8);
#if defined(HAVE_FDOT2)
#pragma unroll
        for (int qq = 0; qq < 4; ++qq) {
          f16x2 wp = {w2v[k][2 * qq], w2v[k][2 * qq + 1]};
          f16x2 sp = {t[2 * qq], t[2 * qq + 1]};
          acc[j] = __builtin_amdgcn_fdot2(sp, wp, acc[j], false);
        }
#else
#pragma unroll
        for (int qq = 0; qq < 8; ++qq)
          acc[j] += (float)t[qq] * (float)w2v[k][qq];
#endif
      }
    }
#pragma unroll
    for (int off = 8; off >= 1; off >>= 1) {
#pragma unroll
      for (int j = 0; j < 4; ++j) acc[j] += __shfl_xor(acc[j], off);
    }
    if (li == 0) {
      for (int j = 0; j < cn; ++j) out[si[j]] = acc[j] + bias2;
    }
  }
}

extern "C" void kernel_launch(void* const* d_in, const int* in_sizes, int n_in,
                              void* d_out, int out_size, void* d_ws, size_t ws_size,
                              hipStream_t stream) {
  const float* z_drug  = (const float*)d_in[0];
  const float* z_react = (const float*)d_in[1];
  const int*   row     = (const int*)d_in[2];
  const int*   col     = (const int*)d_in[3];
  const float* W1      = (const float*)d_in[4];
  const float* b1      = (const float*)d_in[5];
  const float* W2      = (const float*)d_in[6];
  const float* b2      = (const float*)d_in[7];
  float* out = (float*)d_out;

  char* ws = (char*)d_ws;
  size_t off = 0;
  auto alloc = [&](size_t bytes) {
    void* p = ws + off;
    off += (bytes + 255) & ~(size_t)255;
    return p;
  };
  _Float16* wl_f = (_Float16*)alloc((size_t)HIDDEN * HIDDEN * 2);
  _Float16* wr_f = (_Float16*)alloc((size_t)HIDDEN * HIDDEN * 2);
  _Float16* Hd   = (_Float16*)alloc((size_t)NDRUG * HIDDEN * 2);
  _Float16* Hr   = (_Float16*)alloc((size_t)NREACT * HIDDEN * 2);
  int*      cursor = (int*)alloc((size_t)NBKT * CSTRIDE * 4);       // 20 KB padded
  uint64_t* pk     = (uint64_t*)alloc((size_t)NBKT * SLOT * 8);     // 5.2 MB

  w1prep<<<130, 256, 0, stream>>>(W1, wl_f, wr_f, cursor);
  gemm_scatter<<<GEMMBLKS + NSCAT, 256, 0, stream>>>(z_drug, z_react, wl_f, wr_f, b1,
                                                     row, col, Hd, Hr, cursor, pk);
  edge_kernel<<<EBLK, ETHREADS, 0, stream>>>(Hd, Hr, pk, cursor, W2, b2, out);
}

// Round 14
// 62.879 us; speedup vs baseline: 1.2148x; 1.0720x over previous
//
#include <hip/hip_runtime.h>
#include <stdint.h>

#define HIDDEN 512
#define NDRUG 2000
#define NREACT 10000
#define NEDGE 400000

// bucketed near-sort: 250 buckets x 40 cols each (c/40 via mul-shift)
#define NBKT 250
#define HRROWS 40
#define SLOT 2048                 // capacity per bucket (mean ~1600, sigma ~40; +11 sigma)
#define CSTRIDE 16                // cursor padded to 1 int per 64B cache line
#define NSCAT 128                 // scatter blocks (LDS-aggregated)
#define EPB ((NEDGE + NSCAT - 1) / NSCAT)   // 3125 edges per scatter block

// edge kernel: 2 blocks per bucket -> 500 blocks, all co-resident (no tail rounds)
#define BPB2 2
#define EBLK (NBKT * BPB2)        // 500
#define MAXSL 1024                // max slice entries (= 2 * 512 threads, register-held)
#define HRSTRIDE 520              // f16 elems per LDS hr row (512 + 8 pad)
#define ETHREADS 512

__device__ __forceinline__ int col2bkt(int c) { return (c * 6554) >> 18; }  // ==c/40 for c<10000

typedef __attribute__((ext_vector_type(8))) _Float16 f16x8;
typedef __attribute__((ext_vector_type(2))) _Float16 f16x2;
typedef __attribute__((ext_vector_type(4))) float f32x4;
typedef __attribute__((ext_vector_type(8))) float f32x8;
typedef __attribute__((ext_vector_type(4))) float float4v;
typedef __attribute__((ext_vector_type(4))) _Float16 f16x4;

#if defined(__has_builtin)
#if __has_builtin(__builtin_amdgcn_fdot2)
#define HAVE_FDOT2 1
#endif
#endif

// ---------------- w1prep: split W1 into f16 halves + init cursors ----------------
__global__ __launch_bounds__(256) void w1prep(const float* __restrict__ W1,
                                              _Float16* __restrict__ WL,
                                              _Float16* __restrict__ WR,
                                              int* __restrict__ cursor) {
  const int b = blockIdx.x;
  const int tid = threadIdx.x;
  if (b < 128) {
    const int nth = 128 * 256;
    const int NQ = HIDDEN * 2 * HIDDEN / 4;   // 131072 quads
    for (int i = b * 256 + tid; i < NQ; i += nth) {
      int e = i * 4;
      int o = e >> 10, j = e & 1023;
      float4v v = *reinterpret_cast<const float4v*>(W1 + e);
      f16x4 q; q[0]=(_Float16)v[0]; q[1]=(_Float16)v[1]; q[2]=(_Float16)v[2]; q[3]=(_Float16)v[3];
      if (j < HIDDEN) *reinterpret_cast<f16x4*>(WL + o * HIDDEN + j) = q;
      else            *reinterpret_cast<f16x4*>(WR + o * HIDDEN + (j - HIDDEN)) = q;
    }
  } else {
    int i = (b - 128) * 256 + tid;
    if (i < NBKT) cursor[i * CSTRIDE] = i * SLOT;
  }
}

// ---------------- fused gemm (A: f32 reg-staged; B: f16 gload_lds) + scatter ----------------
#define BM 64
#define BN 128
#define BK 32
#define GEMMBLKS 756

__global__ __launch_bounds__(256) void gemm_scatter(
    const float* __restrict__ z_drug, const float* __restrict__ z_react,
    const _Float16* __restrict__ BL, const _Float16* __restrict__ BR,
    const float* __restrict__ bias,
    const int* __restrict__ row, const int* __restrict__ col,
    _Float16* __restrict__ Hd, _Float16* __restrict__ Hr,
    int* __restrict__ cursor, uint64_t* __restrict__ pk)
{
  __shared__ _Float16 As[BM * BK];   // 4 KB
  __shared__ _Float16 Bs[BN * BK];   // 8 KB
  __shared__ int lhist[256];
  __shared__ int lbase[256];

  const int bid = blockIdx.x;
  const int tid = threadIdx.x;

  if (bid >= GEMMBLKS) {
    // ---- scatter branch: block handles edges [e0, e1)
    const int sb = bid - GEMMBLKS;
    const int e0 = sb * EPB;
    const int e1 = (e0 + EPB < NEDGE) ? e0 + EPB : NEDGE;
    if (tid < 256) { lhist[tid] = 0; }
    __syncthreads();
    for (int e = e0 + tid; e < e1; e += 256)
      atomicAdd(&lhist[col2bkt(col[e])], 1);
    __syncthreads();
    if (tid < NBKT) {
      int cnt = lhist[tid];
      lbase[tid] = cnt ? atomicAdd(&cursor[tid * CSTRIDE], cnt) : 0;
      lhist[tid] = 0;
    }
    __syncthreads();
    for (int e = e0 + tid; e < e1; e += 256) {
      int c = col[e];
      int r = row[e];
      int bkt = col2bkt(c);
      int lo = atomicAdd(&lhist[bkt], 1);
      pk[lbase[bkt] + lo] = ((uint64_t)e << 25) | ((uint64_t)r << 14) | (uint64_t)c;
    }
    return;
  }

  // ---- gemm branch: [0,128) drug (32 mb x 4 nb); [128,756) reaction (157 mb x 4 nb)
  const int z = (bid >= 128) ? 1 : 0;
  const int t = z ? bid - 128 : bid;
  const int mb = t >> 2;
  const int nb = t & 3;
  const int M = (z == 0) ? NDRUG : NREACT;
  const float* A = (z == 0) ? z_drug : z_react;
  const _Float16* B = (z == 0) ? BL : BR;
  _Float16* C = (z == 0) ? Hd : Hr;
  const bool has_bias = (z == 0);
  const int K = HIDDEN, N = HIDDEN;

  const int lane = tid & 63;
  const int wid = tid >> 6;     // wn
  const int wn = wid;

  f32x4 acc[4][2];
#pragma unroll
  for (int i = 0; i < 4; ++i)
#pragma unroll
    for (int j = 0; j < 2; ++j) acc[i][j] = (f32x4){0.f, 0.f, 0.f, 0.f};

  const int row0 = mb * BM;
  const int col0 = nb * BN;
  const int r0 = tid >> 2;
  const int q0 = tid & 3;
  const int srow = lane >> 2;
  const int scol = (lane & 3) * 8;

  for (int kt = 0; kt < K; kt += BK) {
    int rA = row0 + r0;
    rA = rA < M ? rA : M - 1;
    f32x8 va = *reinterpret_cast<const f32x8*>(A + (size_t)rA * K + kt + q0 * 8);
    f16x8 afh = __builtin_convertvector(va, f16x8);
    __syncthreads();
    *reinterpret_cast<f16x8*>(As + r0 * BK + q0 * 8) = afh;
#pragma unroll
    for (int i = 0; i < 2; ++i) {
      int rB = col0 + wid * 32 + i * 16 + srow;
      const _Float16* gB = B + (size_t)rB * K + kt + scol;
      _Float16* lB = Bs + (wid * 32 + i * 16) * BK;
      __builtin_amdgcn_global_load_lds(
          (const __attribute__((address_space(1))) void*)gB,
          (__attribute__((address_space(3))) void*)lB, 16, 0, 0);
    }
    __syncthreads();

    const int fr = lane & 15;
    const int kg = (lane >> 4) * 8;
    f16x8 af[4], bfr[2];
#pragma unroll
    for (int mi = 0; mi < 4; ++mi)
      af[mi] = *reinterpret_cast<const f16x8*>(As + (mi * 16 + fr) * BK + kg);
#pragma unroll
    for (int ni = 0; ni < 2; ++ni)
      bfr[ni] = *reinterpret_cast<const f16x8*>(Bs + (wn * 32 + ni * 16 + fr) * BK + kg);
#pragma unroll
    for (int mi = 0; mi < 4; ++mi)
#pragma unroll
      for (int ni = 0; ni < 2; ++ni)
        acc[mi][ni] = __builtin_amdgcn_mfma_f32_16x16x32_f16(af[mi], bfr[ni], acc[mi][ni], 0, 0, 0);
  }

  const int crow = (lane >> 4) * 4;
  const int ccol = lane & 15;
#pragma unroll
  for (int ni = 0; ni < 2; ++ni) {
    const int gc = col0 + wn * 32 + ni * 16 + ccol;
    const float bv = has_bias ? bias[gc] : 0.0f;
#pragma unroll
    for (int mi = 0; mi < 4; ++mi) {
#pragma unroll
      for (int j = 0; j < 4; ++j) {
        const int gr = row0 + mi * 16 + crow + j;
        if (gr < M) C[(size_t)gr * N + gc] = (_Float16)(acc[mi][ni][j] + bv);
      }
    }
  }
}

// ---------------- edge kernel: 500 co-resident blocks, reg-held sort, Hr(40) in LDS ----
__global__ __launch_bounds__(ETHREADS) void edge_kernel(
    const _Float16* __restrict__ Hd, const _Float16* __restrict__ Hr,
    const uint64_t* __restrict__ pk, const int* __restrict__ cursor,
    const float* __restrict__ W2, const float* __restrict__ b2,
    float* __restrict__ out)
{
  __shared__ _Float16 hrs[HRROWS * HRSTRIDE]; // 41.6 KB: the bucket's 40 Hr rows (padded)
  __shared__ uint64_t spk[MAXSL];             // 8 KB col-sorted
  __shared__ int qdesc[MAXSL / 4 + HRROWS];   // quad descriptors
  __shared__ int cnt[HRROWS], cb[HRROWS], cnt2[HRROWS], qoff[HRROWS];
  __shared__ int nqs;

  // bijective bucket->XCD chunked mapping (250 = 8*31 + 2; m204 formula)
  const int bid = blockIdx.x;
  const int porig = bid >> 1;               // 0..249
  const int slice = bid & 1;
  const int xcd = porig & 7;
  const int pidx = porig >> 3;              // 0..31
  const int bucket = (xcd < 2 ? xcd * 32 : 2 * 32 + (xcd - 2) * 31) + pidx;
  const int cbase = bucket * HRROWS;
  const int base = bucket * SLOT;
  const int count = cursor[bucket * CSTRIDE] - base;   // pre-biased cursor
  const int per = (count + BPB2 - 1) / BPB2;
  const int s = slice * per;
  const int e_end0 = (s + per < count) ? s + per : count;
  const int n = (e_end0 > s) ? e_end0 - s : 0;

  const int tid = threadIdx.x;
  const int lane = tid & 63;
  const int li = lane & 15;
  const int wv = tid >> 6;                  // 0..7
  const int gid = wv * 4 + (lane >> 4);     // 0..31: static group id

  // ---- issue Hr preload: wave wv loads rows [wv*5, wv*5+5)
#pragma unroll
  for (int rr2 = 0; rr2 < 5; ++rr2) {
    int rr = wv * 5 + rr2;
    int gr = cbase + rr;                    // <= 9999 exactly
    const _Float16* src = Hr + (size_t)gr * HIDDEN + lane * 8;
    _Float16* dst = hrs + rr * HRSTRIDE;
    __builtin_amdgcn_global_load_lds(
        (const __attribute__((address_space(1))) void*)src,
        (__attribute__((address_space(3))) void*)dst, 16, 0, 0);
  }

  // ---- W2 fragment: lane covers elems li*8 + 128k
  f16x8 w2v[4];
#pragma unroll
  for (int k = 0; k < 4; ++k) {
    const float* p = W2 + li * 8 + k * 128;
    f16x8 q;
#pragma unroll
    for (int j = 0; j < 8; ++j) q[j] = (_Float16)p[j];
    w2v[k] = q;
  }
  const float bias2 = *b2;
  const f16x8 zero8 = (f16x8)(_Float16)0;

  // ---- in-LDS counting sort by local col, entries register-held (n <= 1024 = 2*512)
  if (tid < HRROWS) { cnt[tid] = 0; cnt2[tid] = 0; }
  __syncthreads();
  uint64_t p0 = 0, p1 = 0;
  int b0 = 0, b1 = 0;
  const int i0 = tid, i1 = tid + ETHREADS;
  if (i0 < n) {
    p0 = pk[base + s + i0];
    b0 = (int)(p0 & 0x3FFF) - cbase;
    atomicAdd(&cnt[b0], 1);
  }
  if (i1 < n) {
    p1 = pk[base + s + i1];
    b1 = (int)(p1 & 0x3FFF) - cbase;
    atomicAdd(&cnt[b1], 1);
  }
  __syncthreads();
  if (tid == 0) {
    int acc = 0, qa = 0;
    for (int j = 0; j < HRROWS; ++j) {
      cb[j] = acc; acc += cnt[j];
      qoff[j] = qa; qa += (cnt[j] + 3) >> 2;
    }
    nqs = qa;
  }
  __syncthreads();
  if (i0 < n) { int lo = atomicAdd(&cnt2[b0], 1); spk[cb[b0] + lo] = p0; }
  if (i1 < n) { int lo = atomicAdd(&cnt2[b1], 1); spk[cb[b1] + lo] = p1; }
  __syncthreads();
  if (tid < HRROWS) {
    int j = tid, st = cb[j], len = cnt[j], o = qoff[j];
    for (int q = 0; q < len; q += 4) {
      int cn = len - q; cn = (cn < 4) ? cn : 4;
      qdesc[o++] = j | ((st + q) << 6) | (cn << 17);
    }
  }
  __syncthreads();   // also drains vmcnt -> hrs ready

  // ---- process quads, statically strided
  const int nq = nqs;
  for (int q = gid; q < nq; q += 32) {
    const int d = qdesc[q];
    const int lc = d & 63;
    const int st = (d >> 6) & 2047;
    const int cn = (d >> 17) & 7;

    const _Float16* hd[4];
    int si[4];
#pragma unroll
    for (int j = 0; j < 4; ++j) {
      int jj = (j < cn) ? j : cn - 1;
      uint64_t p = spk[st + jj];
      si[j] = (int)(p >> 25);
      hd[j] = Hd + (size_t)((p >> 14) & 0x7FF) * HIDDEN;
    }

    f16x8 vd[4][4];
#pragma unroll
    for (int j = 0; j < 4; ++j)
#pragma unroll
      for (int k = 0; k < 4; ++k)
        vd[j][k] = *reinterpret_cast<const f16x8*>(hd[j] + li * 8 + k * 128);

    f16x8 hv[4];
#pragma unroll
    for (int k = 0; k < 4; ++k)
      hv[k] = *reinterpret_cast<const f16x8*>(hrs + lc * HRSTRIDE + li * 8 + k * 128);

    float acc[4] = {0.f, 0.f, 0.f, 0.f};
#pragma unroll
    for (int j = 0; j < 4; ++j) {
#pragma unroll
      for (int k = 0; k < 4; ++k) {
        f16x8 t = __builtin_elementwise_max(vd[j][k] + hv[k], zero8);
#if defined(HAVE_FDOT2)
#pragma unroll
        for (int qq = 0; qq < 4; ++qq) {
          f16x2 wp = {w2v[k][2 * qq], w2v[k][2 * qq + 1]};
          f16x2 sp = {t[2 * qq], t[2 * qq + 1]};
          acc[j] = __builtin_amdgcn_fdot2(sp, wp, acc[j], false);
        }
#else
#pragma unroll
        for (int qq = 0; qq < 8; ++qq)
          acc[j] += (float)t[qq] * (float)w2v[k][qq];
#endif
      }
    }
#pragma unroll
    for (int off = 8; off >= 1; off >>= 1) {
#pragma unroll
      for (int j = 0; j < 4; ++j) acc[j] += __shfl_xor(acc[j], off);
    }
    if (li == 0) {
      for (int j = 0; j < cn; ++j) out[si[j]] = acc[j] + bias2;
    }
  }
}

extern "C" void kernel_launch(void* const* d_in, const int* in_sizes, int n_in,
                              void* d_out, int out_size, void* d_ws, size_t ws_size,
                              hipStream_t stream) {
  const float* z_drug  = (const float*)d_in[0];
  const float* z_react = (const float*)d_in[1];
  const int*   row     = (const int*)d_in[2];
  const int*   col     = (const int*)d_in[3];
  const float* W1      = (const float*)d_in[4];
  const float* b1      = (const float*)d_in[5];
  const float* W2      = (const float*)d_in[6];
  const float* b2      = (const float*)d_in[7];
  float* out = (float*)d_out;

  char* ws = (char*)d_ws;
  size_t off = 0;
  auto alloc = [&](size_t bytes) {
    void* p = ws + off;
    off += (bytes + 255) & ~(size_t)255;
    return p;
  };
  _Float16* wl_f = (_Float16*)alloc((size_t)HIDDEN * HIDDEN * 2);
  _Float16* wr_f = (_Float16*)alloc((size_t)HIDDEN * HIDDEN * 2);
  _Float16* Hd   = (_Float16*)alloc((size_t)NDRUG * HIDDEN * 2);
  _Float16* Hr   = (_Float16*)alloc((size_t)NREACT * HIDDEN * 2);
  int*      cursor = (int*)alloc((size_t)NBKT * CSTRIDE * 4);
  uint64_t* pk     = (uint64_t*)alloc((size_t)NBKT * SLOT * 8);     // 4.1 MB

  w1prep<<<130, 256, 0, stream>>>(W1, wl_f, wr_f, cursor);
  gemm_scatter<<<GEMMBLKS + NSCAT, 256, 0, stream>>>(z_drug, z_react, wl_f, wr_f, b1,
                                                     row, col, Hd, Hr, cursor, pk);
  edge_kernel<<<EBLK, ETHREADS, 0, stream>>>(Hd, Hr, pk, cursor, W2, b2, out);
}

// Round 15
// 61.510 us; speedup vs baseline: 1.2418x; 1.0222x over previous
//
#include <hip/hip_runtime.h>
#include <stdint.h>

#define HIDDEN 512
#define NDRUG 2000
#define NREACT 10000
#define NEDGE 400000

// bucketed near-sort: 250 buckets x 40 cols each (c/40 via mul-shift)
#define NBKT 250
#define HRROWS 40
#define SLOT 2048                 // capacity per bucket (mean ~1600, sigma ~40; +11 sigma)
#define CSTRIDE 16                // cursor padded to 1 int per 64B cache line
#define NSCAT 128                 // scatter blocks (LDS-aggregated)
#define EPB ((NEDGE + NSCAT - 1) / NSCAT)   // 3125 edges per scatter block

// edge kernel: 2 blocks per bucket -> 500 blocks, all co-resident (no tail rounds)
#define BPB2 2
#define EBLK (NBKT * BPB2)        // 500
#define MAXSL 1024                // max slice entries (= 2 * 512 threads, register-held)
#define HRSTRIDE 520              // f16 elems per LDS hr row (512 + 8 pad)
#define ETHREADS 512

__device__ __forceinline__ int col2bkt(int c) { return (c * 6554) >> 18; }  // ==c/40 for c<10000

typedef __attribute__((ext_vector_type(8))) _Float16 f16x8;
typedef __attribute__((ext_vector_type(2))) _Float16 f16x2;
typedef __attribute__((ext_vector_type(4))) float f32x4;
typedef __attribute__((ext_vector_type(8))) float f32x8;
typedef __attribute__((ext_vector_type(4))) float float4v;
typedef __attribute__((ext_vector_type(4))) _Float16 f16x4;

#if defined(__has_builtin)
#if __has_builtin(__builtin_amdgcn_fdot2)
#define HAVE_FDOT2 1
#endif
#endif

// ---------------- w1prep: split W1 into f16 halves + init cursors ----------------
__global__ __launch_bounds__(256) void w1prep(const float* __restrict__ W1,
                                              _Float16* __restrict__ WL,
                                              _Float16* __restrict__ WR,
                                              int* __restrict__ cursor) {
  const int b = blockIdx.x;
  const int tid = threadIdx.x;
  if (b < 128) {
    const int nth = 128 * 256;
    const int NQ = HIDDEN * 2 * HIDDEN / 4;   // 131072 quads
    for (int i = b * 256 + tid; i < NQ; i += nth) {
      int e = i * 4;
      int o = e >> 10, j = e & 1023;
      float4v v = *reinterpret_cast<const float4v*>(W1 + e);
      f16x4 q; q[0]=(_Float16)v[0]; q[1]=(_Float16)v[1]; q[2]=(_Float16)v[2]; q[3]=(_Float16)v[3];
      if (j < HIDDEN) *reinterpret_cast<f16x4*>(WL + o * HIDDEN + j) = q;
      else            *reinterpret_cast<f16x4*>(WR + o * HIDDEN + (j - HIDDEN)) = q;
    }
  } else {
    int i = (b - 128) * 256 + tid;
    if (i < NBKT) cursor[i * CSTRIDE] = i * SLOT;
  }
}

// ---------------- fused gemm (double-buffered; A: f32 reg-staged; B: f16 gload_lds) + scatter --
#define BM 64
#define BN 128
#define BK 32
#define GEMMBLKS 756
#define ABUF (BM * BK)   // 2048 f16
#define BBUF (BN * BK)   // 4096 f16

__global__ __launch_bounds__(256) void gemm_scatter(
    const float* __restrict__ z_drug, const float* __restrict__ z_react,
    const _Float16* __restrict__ BL, const _Float16* __restrict__ BR,
    const float* __restrict__ bias,
    const int* __restrict__ row, const int* __restrict__ col,
    _Float16* __restrict__ Hd, _Float16* __restrict__ Hr,
    int* __restrict__ cursor, uint64_t* __restrict__ pk)
{
  __shared__ _Float16 As[2 * ABUF];   // 8 KB (double-buffered)
  __shared__ _Float16 Bs[2 * BBUF];   // 16 KB
  __shared__ int lhist[256];
  __shared__ int lbase[256];

  const int bid = blockIdx.x;
  const int tid = threadIdx.x;

  if (bid >= GEMMBLKS) {
    // ---- scatter branch: block handles edges [e0, e1)
    const int sb = bid - GEMMBLKS;
    const int e0 = sb * EPB;
    const int e1 = (e0 + EPB < NEDGE) ? e0 + EPB : NEDGE;
    if (tid < 256) { lhist[tid] = 0; }
    __syncthreads();
    for (int e = e0 + tid; e < e1; e += 256)
      atomicAdd(&lhist[col2bkt(col[e])], 1);
    __syncthreads();
    if (tid < NBKT) {
      int cnt = lhist[tid];
      lbase[tid] = cnt ? atomicAdd(&cursor[tid * CSTRIDE], cnt) : 0;
      lhist[tid] = 0;
    }
    __syncthreads();
    for (int e = e0 + tid; e < e1; e += 256) {
      int c = col[e];
      int r = row[e];
      int bkt = col2bkt(c);
      int lo = atomicAdd(&lhist[bkt], 1);
      pk[lbase[bkt] + lo] = ((uint64_t)e << 25) | ((uint64_t)r << 14) | (uint64_t)c;
    }
    return;
  }

  // ---- gemm branch: [0,128) drug (32 mb x 4 nb); [128,756) reaction (157 mb x 4 nb)
  const int z = (bid >= 128) ? 1 : 0;
  const int t0 = z ? bid - 128 : bid;
  const int mb = t0 >> 2;
  const int nb = t0 & 3;
  const int M = (z == 0) ? NDRUG : NREACT;
  const float* A = (z == 0) ? z_drug : z_react;
  const _Float16* B = (z == 0) ? BL : BR;
  _Float16* C = (z == 0) ? Hd : Hr;
  const bool has_bias = (z == 0);
  const int K = HIDDEN, N = HIDDEN;
  const int NT = K / BK;   // 16

  const int lane = tid & 63;
  const int wid = tid >> 6;     // wn
  const int wn = wid;

  f32x4 acc[4][2];
#pragma unroll
  for (int i = 0; i < 4; ++i)
#pragma unroll
    for (int j = 0; j < 2; ++j) acc[i][j] = (f32x4){0.f, 0.f, 0.f, 0.f};

  const int row0 = mb * BM;
  const int col0 = nb * BN;
  const int r0 = tid >> 2;
  const int q0 = tid & 3;
  const int srow = lane >> 2;
  const int scol = (lane & 3) * 8;

  // A row is fixed across kt; clamp once
  int rA = row0 + r0;
  rA = rA < M ? rA : M - 1;
  const float* Arow = A + (size_t)rA * K + q0 * 8;

  // ---- prologue: stage tile 0 into buf0, prefetch A for tile 1
  {
    f32x8 va0 = *reinterpret_cast<const f32x8*>(Arow + 0);
    *reinterpret_cast<f16x8*>(As + r0 * BK + q0 * 8) = __builtin_convertvector(va0, f16x8);
#pragma unroll
    for (int i = 0; i < 2; ++i) {
      int rB = col0 + wid * 32 + i * 16 + srow;
      const _Float16* gB = B + (size_t)rB * K + 0 + scol;
      _Float16* lB = Bs + (wid * 32 + i * 16) * BK;
      __builtin_amdgcn_global_load_lds(
          (const __attribute__((address_space(1))) void*)gB,
          (__attribute__((address_space(3))) void*)lB, 16, 0, 0);
    }
  }
  f32x8 va_n = *reinterpret_cast<const f32x8*>(Arow + BK);   // tile 1 A data

  const int fr = lane & 15;
  const int kg = (lane >> 4) * 8;

  for (int t = 0; t < NT; ++t) {
    const int cur = t & 1;
    __syncthreads();   // buf[cur] staged (drains vm+lgkm); buf[cur^1] readers done
    if (t < NT - 1) {
      const int ktn = (t + 1) * BK;
      // B: async global->LDS into buf[cur^1] (overlaps MFMA below until next barrier)
#pragma unroll
      for (int i = 0; i < 2; ++i) {
        int rB = col0 + wid * 32 + i * 16 + srow;
        const _Float16* gB = B + (size_t)rB * K + ktn + scol;
        _Float16* lB = Bs + (cur ^ 1) * BBUF + (wid * 32 + i * 16) * BK;
        __builtin_amdgcn_global_load_lds(
            (const __attribute__((address_space(1))) void*)gB,
            (__attribute__((address_space(3))) void*)lB, 16, 0, 0);
      }
      // A: cvt prefetched regs, ds_write into buf[cur^1]
      *reinterpret_cast<f16x8*>(As + (cur ^ 1) * ABUF + r0 * BK + q0 * 8) =
          __builtin_convertvector(va_n, f16x8);
      if (t < NT - 2)
        va_n = *reinterpret_cast<const f32x8*>(Arow + (t + 2) * BK);
    }
    // compute from buf[cur]
    f16x8 af[4], bfr[2];
#pragma unroll
    for (int mi = 0; mi < 4; ++mi)
      af[mi] = *reinterpret_cast<const f16x8*>(As + cur * ABUF + (mi * 16 + fr) * BK + kg);
#pragma unroll
    for (int ni = 0; ni < 2; ++ni)
      bfr[ni] = *reinterpret_cast<const f16x8*>(Bs + cur * BBUF + (wn * 32 + ni * 16 + fr) * BK + kg);
#pragma unroll
    for (int mi = 0; mi < 4; ++mi)
#pragma unroll
      for (int ni = 0; ni < 2; ++ni)
        acc[mi][ni] = __builtin_amdgcn_mfma_f32_16x16x32_f16(af[mi], bfr[ni], acc[mi][ni], 0, 0, 0);
  }

  const int crow = (lane >> 4) * 4;
  const int ccol = lane & 15;
#pragma unroll
  for (int ni = 0; ni < 2; ++ni) {
    const int gc = col0 + wn * 32 + ni * 16 + ccol;
    const float bv = has_bias ? bias[gc] : 0.0f;
#pragma unroll
    for (int mi = 0; mi < 4; ++mi) {
#pragma unroll
      for (int j = 0; j < 4; ++j) {
        const int gr = row0 + mi * 16 + crow + j;
        if (gr < M) C[(size_t)gr * N + gc] = (_Float16)(acc[mi][ni][j] + bv);
      }
    }
  }
}

// ---------------- edge kernel: 500 co-resident blocks, reg-held sort, Hr(40) in LDS ----
__global__ __launch_bounds__(ETHREADS) void edge_kernel(
    const _Float16* __restrict__ Hd, const _Float16* __restrict__ Hr,
    const uint64_t* __restrict__ pk, const int* __restrict__ cursor,
    const float* __restrict__ W2, const float* __restrict__ b2,
    float* __restrict__ out)
{
  __shared__ _Float16 hrs[HRROWS * HRSTRIDE]; // 41.6 KB: the bucket's 40 Hr rows (padded)
  __shared__ uint64_t spk[MAXSL];             // 8 KB col-sorted
  __shared__ int qdesc[MAXSL / 4 + HRROWS];   // quad descriptors
  __shared__ int cnt[HRROWS], cb[HRROWS], cnt2[HRROWS], qoff[HRROWS];
  __shared__ int nqs;

  // bijective bucket->XCD chunked mapping (250 = 8*31 + 2; m204 formula)
  const int bid = blockIdx.x;
  const int porig = bid >> 1;               // 0..249
  const int slice = bid & 1;
  const int xcd = porig & 7;
  const int pidx = porig >> 3;              // 0..31
  const int bucket = (xcd < 2 ? xcd * 32 : 2 * 32 + (xcd - 2) * 31) + pidx;
  const int cbase = bucket * HRROWS;
  const int base = bucket * SLOT;
  const int count = cursor[bucket * CSTRIDE] - base;   // pre-biased cursor
  const int per = (count + BPB2 - 1) / BPB2;
  const int s = slice * per;
  const int e_end0 = (s + per < count) ? s + per : count;
  const int n = (e_end0 > s) ? e_end0 - s : 0;

  const int tid = threadIdx.x;
  const int lane = tid & 63;
  const int li = lane & 15;
  const int wv = tid >> 6;                  // 0..7
  const int gid = wv * 4 + (lane >> 4);     // 0..31: static group id

  // ---- issue Hr preload: wave wv loads rows [wv*5, wv*5+5)
#pragma unroll
  for (int rr2 = 0; rr2 < 5; ++rr2) {
    int rr = wv * 5 + rr2;
    int gr = cbase + rr;                    // <= 9999 exactly
    const _Float16* src = Hr + (size_t)gr * HIDDEN + lane * 8;
    _Float16* dst = hrs + rr * HRSTRIDE;
    __builtin_amdgcn_global_load_lds(
        (const __attribute__((address_space(1))) void*)src,
        (__attribute__((address_space(3))) void*)dst, 16, 0, 0);
  }

  // ---- W2 fragment: lane covers elems li*8 + 128k
  f16x8 w2v[4];
#pragma unroll
  for (int k = 0; k < 4; ++k) {
    const float* p = W2 + li * 8 + k * 128;
    f16x8 q;
#pragma unroll
    for (int j = 0; j < 8; ++j) q[j] = (_Float16)p[j];
    w2v[k] = q;
  }
  const float bias2 = *b2;
  const f16x8 zero8 = (f16x8)(_Float16)0;

  // ---- counting sort by local col, entries register-held (n <= 1024 = 2*512)
  if (tid < HRROWS) { cnt[tid] = 0; cnt2[tid] = 0; }
  __syncthreads();
  uint64_t p0 = 0, p1 = 0;
  int b0 = 0, b1 = 0;
  const int i0 = tid, i1 = tid + ETHREADS;
  if (i0 < n) {
    p0 = pk[base + s + i0];
    b0 = (int)(p0 & 0x3FFF) - cbase;
    atomicAdd(&cnt[b0], 1);
  }
  if (i1 < n) {
    p1 = pk[base + s + i1];
    b1 = (int)(p1 & 0x3FFF) - cbase;
    atomicAdd(&cnt[b1], 1);
  }
  __syncthreads();
  // parallel exclusive scan over 40 bins (wave 0, shfl_up)
  if (tid < 64) {
    int j = tid;
    int c = (j < HRROWS) ? cnt[j] : 0;
    int qc = (c + 3) >> 2;
    int ic = c, iq = qc;
#pragma unroll
    for (int off = 1; off < 64; off <<= 1) {
      int u = __shfl_up(ic, off);
      int v = __shfl_up(iq, off);
      if (lane >= off) { ic += u; iq += v; }
    }
    if (j < HRROWS) { cb[j] = ic - c; qoff[j] = iq - qc; }
    if (j == HRROWS - 1) nqs = iq;
  }
  __syncthreads();
  if (i0 < n) { int lo = atomicAdd(&cnt2[b0], 1); spk[cb[b0] + lo] = p0; }
  if (i1 < n) { int lo = atomicAdd(&cnt2[b1], 1); spk[cb[b1] + lo] = p1; }
  __syncthreads();
  if (tid < HRROWS) {
    int j = tid, st = cb[j], len = cnt[j], o = qoff[j];
    for (int q = 0; q < len; q += 4) {
      int cn = len - q; cn = (cn < 4) ? cn : 4;
      qdesc[o++] = j | ((st + q) << 6) | (cn << 17);
    }
  }
  __syncthreads();   // also drains vmcnt -> hrs ready

  // ---- process quads, statically strided, descriptor prefetched one iter ahead
  const int nq = nqs;
  int q = gid;
  int d = (q < nq) ? qdesc[q] : 0;
  while (q < nq) {
    const int qn = q + 32;
    const int dn = (qn < nq) ? qdesc[qn] : 0;   // prefetch next descriptor

    const int lc = d & 63;
    const int st = (d >> 6) & 2047;
    const int cn = (d >> 17) & 7;

    const _Float16* hd[4];
    int si[4];
#pragma unroll
    for (int j = 0; j < 4; ++j) {
      int jj = (j < cn) ? j : cn - 1;
      uint64_t p = spk[st + jj];
      si[j] = (int)(p >> 25);
      hd[j] = Hd + (size_t)((p >> 14) & 0x7FF) * HIDDEN;
    }

    f16x8 vd[4][4];
#pragma unroll
    for (int j = 0; j < 4; ++j)
#pragma unroll
      for (int k = 0; k < 4; ++k)
        vd[j][k] = *reinterpret_cast<const f16x8*>(hd[j] + li * 8 + k * 128);

    f16x8 hv[4];
#pragma unroll
    for (int k = 0; k < 4; ++k)
      hv[k] = *reinterpret_cast<const f16x8*>(hrs + lc * HRSTRIDE + li * 8 + k * 128);

    float acc[4] = {0.f, 0.f, 0.f, 0.f};
#pragma unroll
    for (int j = 0; j < 4; ++j) {
#pragma unroll
      for (int k = 0; k < 4; ++k) {
        f16x8 t = __builtin_elementwise_max(vd[j][k] + hv[k], zero8);
#if defined(HAVE_FDOT2)
#pragma unroll
        for (int qq = 0; qq < 4; ++qq) {
          f16x2 wp = {w2v[k][2 * qq], w2v[k][2 * qq + 1]};
          f16x2 sp = {t[2 * qq], t[2 * qq + 1]};
          acc[j] = __builtin_amdgcn_fdot2(sp, wp, acc[j], false);
        }
#else
#pragma unroll
        for (int qq = 0; qq < 8; ++qq)
          acc[j] += (float)t[qq] * (float)w2v[k][qq];
#endif
      }
    }
#pragma unroll
    for (int off = 8; off >= 1; off >>= 1) {
#pragma unroll
      for (int j = 0; j < 4; ++j) acc[j] += __shfl_xor(acc[j], off);
    }
    if (li == 0) {
      for (int j = 0; j < cn; ++j) out[si[j]] = acc[j] + bias2;
    }
    q = qn; d = dn;
  }
}

extern "C" void kernel_launch(void* const* d_in, const int* in_sizes, int n_in,
                              void* d_out, int out_size, void* d_ws, size_t ws_size,
                              hipStream_t stream) {
  const float* z_drug  = (const float*)d_in[0];
  const float* z_react = (const float*)d_in[1];
  const int*   row     = (const int*)d_in[2];
  const int*   col     = (const int*)d_in[3];
  const float* W1      = (const float*)d_in[4];
  const float* b1      = (const float*)d_in[5];
  const float* W2      = (const float*)d_in[6];
  const float* b2      = (const float*)d_in[7];
  float* out = (float*)d_out;

  char* ws = (char*)d_ws;
  size_t off = 0;
  auto alloc = [&](size_t bytes) {
    void* p = ws + off;
    off += (bytes + 255) & ~(size_t)255;
    return p;
  };
  _Float16* wl_f = (_Float16*)alloc((size_t)HIDDEN * HIDDEN * 2);
  _Float16* wr_f = (_Float16*)alloc((size_t)HIDDEN * HIDDEN * 2);
  _Float16* Hd   = (_Float16*)alloc((size_t)NDRUG * HIDDEN * 2);
  _Float16* Hr   = (_Float16*)alloc((size_t)NREACT * HIDDEN * 2);
  int*      cursor = (int*)alloc((size_t)NBKT * CSTRIDE * 4);
  uint64_t* pk     = (uint64_t*)alloc((size_t)NBKT * SLOT * 8);     // 4.1 MB

  w1prep<<<130, 256, 0, stream>>>(W1, wl_f, wr_f, cursor);
  gemm_scatter<<<GEMMBLKS + NSCAT, 256, 0, stream>>>(z_drug, z_react, wl_f, wr_f, b1,
                                                     row, col, Hd, Hr, cursor, pk);
  edge_kernel<<<EBLK, ETHREADS, 0, stream>>>(Hd, Hr, pk, cursor, W2, b2, out);
}